// Round 13
// baseline (1304.218 us; speedup 1.0000x reference)
//
#include <hip/hip_runtime.h>
#include <math.h>

constexpr int B_ = 32, N_ = 67, D_ = 128, H_ = 8, DH_ = 16, L_ = 3;
constexpr int NN_ = N_ * N_;          // 4489
constexpr int RN_ = B_ * N_;          // 2144
constexpr int RE_ = B_ * NN_;         // 143648
constexpr int DOUT_ = 10;

typedef __attribute__((ext_vector_type(8))) short short8;
typedef __attribute__((ext_vector_type(4))) float f32x4;

// branchless tanh-approx GELU
__device__ __forceinline__ float gelu_f(float x) {
  float u = x * (0.7978845608028654f + 0.035677408136f * x * x);
  float e = __expf(-2.f * u);
  return x * (1.f / (1.f + e));
}
__device__ __forceinline__ ushort f2b(float x) {
  union { float f; unsigned u; } v; v.f = x;
  return (ushort)((v.u + 0x7FFFu + ((v.u >> 16) & 1u)) >> 16);
}
__device__ __forceinline__ float b2f(ushort u) {
  union { unsigned u; float f; } v; v.u = (unsigned)u << 16; return v.f;
}

// ---------------- precompute: combined weights (Wao@Wl0, We1@Wel0) ----------------
__global__ void k_comb(const float* __restrict__ Wao, const float* __restrict__ bao,
                       const float* __restrict__ Wl0, const float* __restrict__ bl0,
                       const float* __restrict__ We1, const float* __restrict__ be1,
                       const float* __restrict__ Wel0, const float* __restrict__ bel0,
                       float* WcN, float* bcN, float* WcE, float* bcE) {
  int t = blockIdx.x * blockDim.x + threadIdx.x;
  const int half = L_ * D_ * D_;
  if (t >= 2 * half) return;
  int which = t / half;
  int u = t - which * half;
  int l = u / (D_ * D_);
  int ij = u - l * (D_ * D_);
  int i = ij >> 7, j = ij & 127;
  const float* A  = (which == 0 ? Wao : We1) + (size_t)l * D_ * D_;
  const float* Bm = (which == 0 ? Wl0 : Wel0) + (size_t)l * D_ * D_;
  float s = 0.f;
  for (int k = 0; k < D_; k++) s += A[i * D_ + k] * Bm[k * D_ + j];
  if (which == 0) WcN[u] = s; else WcE[u] = s;
  if (i == 0) {
    const float* ba = (which == 0 ? bao : be1) + l * D_;
    const float* bl = (which == 0 ? bl0 : bel0) + l * D_;
    float sb = 0.f;
    for (int k = 0; k < D_; k++) sb += ba[k] * Bm[k * D_ + j];
    if (which == 0) bcN[l * D_ + j] = sb + bl[j]; else bcE[l * D_ + j] = sb + bl[j];
  }
}

// ---------------- precompute: fragment-major bf16 weights ----------------
__device__ __forceinline__ float enc_src(const float* src, int K, int C, int NKS, int r, int l) {
  int frag = r >> 9;
  int within = r & 511;
  int lane = within >> 3, j = within & 7;
  int cf = frag / NKS, ks = frag - cf * NKS;
  int k = ks * 32 + (lane >> 4) * 8 + j;
  int c = cf * 16 + (lane & 15);
  return src[(size_t)l * K * C + (size_t)k * C + c];
}

__global__ void k_prepw(const float* __restrict__ Wqkve, const float* __restrict__ We,
                        const float* __restrict__ WcE, const float* __restrict__ mW1,
                        const float* __restrict__ mW2,
                        ushort* wq, ushort* we, ushort* wce, ushort* w1, ushort* w2) {
  int t = blockIdx.x * 256 + threadIdx.x;
  const int S0 = L_ * 49152, S1 = L_ * 32768, S2 = L_ * 16384, S3 = L_ * 32768, S4 = L_ * 32768;
  if (t < S0) { int l = t / 49152, r = t % 49152; wq[t]  = f2b(enc_src(Wqkve, 128, 384, 4, r, l)); return; }
  t -= S0;
  if (t < S1) { int l = t / 32768, r = t % 32768; we[t]  = f2b(enc_src(We,   256, 128, 8, r, l)); return; }
  t -= S1;
  if (t < S2) { int l = t / 16384, r = t % 16384; wce[t] = f2b(enc_src(WcE,  128, 128, 4, r, l)); return; }
  t -= S2;
  if (t < S3) { int l = t / 32768, r = t % 32768; w1[t]  = f2b(enc_src(mW1,  128, 256, 4, r, l)); return; }
  t -= S3;
  if (t < S4) { int l = t / 32768, r = t % 32768; w2[t]  = f2b(enc_src(mW2,  256, 128, 8, r, l)); return; }
}

// ---------------- precompute: folded input-embed vectors ----------------
__global__ void k_vecs(const float* pbW, const float* pbb, const float* niW, const float* nib,
                       const float* pwW, const float* pwb, const float* eiW, const float* eib,
                       float* vecs) {
  int j = threadIdx.x;
  if (j >= D_) return;
  float u = 0, c = 0, v = 0, ce = 0;
  for (int k = 0; k < D_; k++) {
    u  += pbW[k] * niW[k * D_ + j];
    c  += pbb[k] * niW[k * D_ + j];
    v  += pwW[k] * eiW[k * D_ + j];
    ce += pwb[k] * eiW[k * D_ + j];
  }
  vecs[j] = u; vecs[D_ + j] = c + nib[j]; vecs[2 * D_ + j] = v; vecs[3 * D_ + j] = ce + eib[j];
}

// ---------------- init node / edge ----------------
__global__ void k_init_node(const float* __restrict__ b0, const float* __restrict__ b1,
                            const float* __restrict__ b2, const float* __restrict__ vecs,
                            const float* __restrict__ pos, float* __restrict__ node) {
  int idx = blockIdx.x * blockDim.x + threadIdx.x;
  if (idx >= RN_ * D_) return;
  int r = idx >> 7, d = idx & 127;
  int b = r / N_, n = r - b * N_;
  float nf = 0.f;
  if (n >= 2 && n < 34)       nf = b0[b * 32 + n - 2];
  else if (n >= 34 && n < 66) nf = b1[b * 32 + n - 34];
  else if (n == 66)           nf = b2[b];
  int pr = (n == 0) ? 0 : (n == 1) ? 1 : (n < 34) ? 2 : (n < 66) ? 3 : 4;
  node[idx] = nf * vecs[d] + vecs[D_ + d] + pos[pr * D_ + d];
}

__global__ void k_init_edge(const float* __restrict__ w0, const float* __restrict__ w1,
                            const float* __restrict__ w2, const float* __restrict__ vecs,
                            ushort* __restrict__ edge) {
  int idx = blockIdx.x * blockDim.x + threadIdx.x;
  if (idx >= RE_ * D_) return;
  int r = idx >> 7, d = idx & 127;
  int b = r / NN_;
  int rem = r - b * NN_;
  int n = rem / N_, m = rem - n * N_;
  float ef = 0.f;
  if (n < 2)        { if (m >= 2 && m < 34)  ef = w0[(b * 2 + n) * 32 + (m - 2)]; }
  else if (n < 34)  { if (m >= 34 && m < 66) ef = w1[(b * 32 + (n - 2)) * 32 + (m - 34)]; }
  else if (n < 66)  { if (m == 66)           ef = w2[b * 32 + (n - 34)]; }
  edge[idx] = f2b(ef * vecs[2 * D_ + d] + vecs[3 * D_ + d]);
}

// ---------------- fused node LN + QKV projection (no bias) ----------------
__global__ __launch_bounds__(256) void k_lnqkv(
    const float* __restrict__ node, const float* __restrict__ g, const float* __restrict__ bb,
    const float* __restrict__ W, float* __restrict__ out) {
  __shared__ float As[16][68];
  __shared__ float Wsh[16][68];
  __shared__ float stmu[64], strs[64];
  int r0 = blockIdx.x * 64, c0 = blockIdx.y * 64;
  int tid = threadIdx.x;
  {
    int row = tid >> 2, part = tid & 3;
    int gr = r0 + row;
    int grc = (gr < RN_) ? gr : 0;
    const float* x = node + (size_t)grc * 128 + part * 32;
    float s = 0.f, q = 0.f;
#pragma unroll
    for (int i = 0; i < 8; i++) {
      float4 v = *reinterpret_cast<const float4*>(&x[i * 4]);
      s += v.x + v.y + v.z + v.w;
      q += v.x * v.x + v.y * v.y + v.z * v.z + v.w * v.w;
    }
    for (int o = 1; o < 4; o <<= 1) { s += __shfl_xor(s, o); q += __shfl_xor(q, o); }
    if (part == 0) {
      float mu = s * (1.f / 128.f);
      stmu[row] = mu;
      strs[row] = rsqrtf(q * (1.f / 128.f) - mu * mu + 1e-5f);
    }
  }
  __syncthreads();
  int tr = tid >> 4, tc = tid & 15;
  float acc[4][4] = {};
  for (int kk = 0; kk < 128; kk += 16) {
#pragma unroll
    for (int i = 0; i < 4; i++) {
      int lin = tid + i * 256;
      int r_in = lin >> 4, k_in = lin & 15;
      int r = r0 + r_in;
      float v = 0.f;
      if (r < RN_) {
        int k = kk + k_in;
        v = (node[(size_t)r * 128 + k] - stmu[r_in]) * strs[r_in] * g[k] + bb[k];
      }
      As[k_in][r_in] = v;
    }
#pragma unroll
    for (int i = 0; i < 4; i++) {
      int lin = tid + i * 256;
      int k_in = lin >> 6, c_in = lin & 63;
      Wsh[k_in][c_in] = W[(size_t)(kk + k_in) * 384 + c0 + c_in];
    }
    __syncthreads();
#pragma unroll
    for (int k = 0; k < 16; k++) {
      float4 a4 = *reinterpret_cast<const float4*>(&As[k][tr * 4]);
      float4 b4 = *reinterpret_cast<const float4*>(&Wsh[k][tc * 4]);
      float av[4] = {a4.x, a4.y, a4.z, a4.w};
      float bv[4] = {b4.x, b4.y, b4.z, b4.w};
#pragma unroll
      for (int i = 0; i < 4; i++)
#pragma unroll
        for (int j = 0; j < 4; j++) acc[i][j] += av[i] * bv[j];
    }
    __syncthreads();
  }
#pragma unroll
  for (int i = 0; i < 4; i++) {
    int r = r0 + tr * 4 + i;
    if (r >= RN_) continue;
#pragma unroll
    for (int j = 0; j < 4; j++) {
      int c = c0 + tc * 4 + j;
      out[(size_t)r * 384 + c] = acc[i][j];
    }
  }
}

// ---------------- fused node residual + MLP ----------------
__global__ __launch_bounds__(256) void k_nodemlp(
    float* __restrict__ node, const float* __restrict__ obuf,
    const float* __restrict__ WcN, const float* __restrict__ bcN,
    const float* __restrict__ g, const float* __restrict__ bb,
    const float* __restrict__ nW1, const float* __restrict__ nb1,
    const float* __restrict__ nW2, const float* __restrict__ nb2) {
  __shared__ float As[16][17];
  __shared__ float Wsh[16][132];
  __shared__ ushort Hs[16][136];
  __shared__ ushort Ts[16][264];
  int r0 = blockIdx.x * 16;
  int tid = threadIdx.x;
  int tr = tid >> 4, tc = tid & 15;
  size_t grow = (size_t)(r0 + tr) * 128;

  auto stageW = [&](const float* src, int ld, int kk, int cbase) {
    int k = tid & 15, cp = tid >> 4;
    const float* s = &src[(size_t)(kk + k) * ld + cbase + cp * 8];
    float* d = &Wsh[k][cp * 8];
#pragma unroll
    for (int j = 0; j < 8; j++) d[j] = s[j];
  };

  float acc[8] = {};
  for (int kk = 0; kk < 128; kk += 16) {
    As[tr][tc] = obuf[grow + kk + tc];
    stageW(WcN, 128, kk, 0);
    __syncthreads();
#pragma unroll
    for (int k = 0; k < 16; k++) {
      float a = As[tr][k];
#pragma unroll
      for (int j = 0; j < 8; j++) acc[j] += a * Wsh[k][tc * 8 + j];
    }
    __syncthreads();
  }
  float nd[8];
  float s = 0.f, q = 0.f;
#pragma unroll
  for (int j = 0; j < 8; j++) {
    int c = tc * 8 + j;
    float v = node[grow + c] + acc[j] + bcN[c];
    nd[j] = v; s += v; q += v * v;
  }
  for (int o = 1; o < 16; o <<= 1) { s += __shfl_xor(s, o); q += __shfl_xor(q, o); }
  float mu = s * (1.f / 128.f);
  float rs = rsqrtf(q * (1.f / 128.f) - mu * mu + 1e-5f);
#pragma unroll
  for (int j = 0; j < 8; j++) {
    int c = tc * 8 + j;
    Hs[tr][c] = f2b((nd[j] - mu) * rs * g[c] + bb[c]);
  }
  for (int ch = 0; ch < 2; ch++) {
    float a2[8] = {};
    for (int kk = 0; kk < 128; kk += 16) {
      __syncthreads();
      stageW(nW1, 256, kk, ch * 128);
      __syncthreads();
#pragma unroll
      for (int k = 0; k < 16; k++) {
        float a = b2f(Hs[tr][kk + k]);
#pragma unroll
        for (int j = 0; j < 8; j++) a2[j] += a * Wsh[k][tc * 8 + j];
      }
    }
#pragma unroll
    for (int j = 0; j < 8; j++) {
      int c = ch * 128 + tc * 8 + j;
      Ts[tr][c] = f2b(gelu_f(a2[j] + nb1[c]));
    }
  }
  float a3[8] = {};
  for (int kk = 0; kk < 256; kk += 16) {
    __syncthreads();
    stageW(nW2, 128, kk, 0);
    __syncthreads();
#pragma unroll
    for (int k = 0; k < 16; k++) {
      float a = b2f(Ts[tr][kk + k]);
#pragma unroll
      for (int j = 0; j < 8; j++) a3[j] += a * Wsh[k][tc * 8 + j];
    }
  }
#pragma unroll
  for (int j = 0; j < 8; j++) {
    int c = tc * 8 + j;
    node[grow + c] = nd[j] + a3[j] + nb2[c];
  }
}

// ---------------- fused rvec/cvec ----------------
__global__ __launch_bounds__(256) void k_nvec(
    const float* __restrict__ node, const float* __restrict__ rmean, const float* __restrict__ cmean,
    const float* __restrict__ Ws, const float* __restrict__ Wer,
    const float* __restrict__ Wt, const float* __restrict__ Wec,
    const float* __restrict__ bs, const float* __restrict__ be, const float* __restrict__ bt,
    float* __restrict__ rvec, float* __restrict__ cvec) {
  __shared__ float Ash[16][68];
  __shared__ float Wsh[16][68];
  int which = blockIdx.z;
  const float* A2 = which ? cmean : rmean;
  const float* W1 = which ? Wt : Ws;
  const float* W2 = which ? Wec : Wer;
  float* out = which ? cvec : rvec;
  int r0 = blockIdx.x * 64, c0 = blockIdx.y * 64;
  int tid = threadIdx.x, tr = tid >> 4, tc = tid & 15;
  float acc[4][4] = {};
  for (int kk = 0; kk < 256; kk += 16) {
#pragma unroll
    for (int i = 0; i < 4; i++) {
      int lin = tid + i * 256;
      int r_in = lin >> 4, k_in = lin & 15;
      int r = r0 + r_in, k = kk + k_in;
      float v = 0.f;
      if (r < RN_) v = (k < 128) ? node[(size_t)r * 128 + k] : A2[(size_t)r * 128 + (k - 128)];
      Ash[k_in][r_in] = v;
    }
#pragma unroll
    for (int i = 0; i < 4; i++) {
      int lin = tid + i * 256;
      int k_in = lin >> 6, c_in = lin & 63;
      int k = kk + k_in, c = c0 + c_in;
      Wsh[k_in][c_in] = (k < 128) ? W1[(size_t)k * 128 + c] : W2[(size_t)(k - 128) * 128 + c];
    }
    __syncthreads();
#pragma unroll
    for (int k = 0; k < 16; k++) {
      float4 a4 = *reinterpret_cast<const float4*>(&Ash[k][tr * 4]);
      float4 b4 = *reinterpret_cast<const float4*>(&Wsh[k][tc * 4]);
      float av[4] = {a4.x, a4.y, a4.z, a4.w};
      float bv[4] = {b4.x, b4.y, b4.z, b4.w};
#pragma unroll
      for (int i = 0; i < 4; i++)
#pragma unroll
        for (int j = 0; j < 4; j++) acc[i][j] += av[i] * bv[j];
    }
    __syncthreads();
  }
#pragma unroll
  for (int i = 0; i < 4; i++) {
    int r = r0 + tr * 4 + i;
    if (r >= RN_) continue;
#pragma unroll
    for (int j = 0; j < 4; j++) {
      int c = c0 + tc * 4 + j;
      float bias = which ? bt[c] : (bs[c] + be[c]);
      out[(size_t)r * 128 + c] = acc[i][j] + bias;
    }
  }
}

// ---------------- fused per-(b,n) attention: wave-owned heads, 1 barrier ----------------
__global__ __launch_bounds__(256, 4) void k_eattn(
    const ushort* __restrict__ edge, const float* __restrict__ qkvn,
    const ushort* __restrict__ wqf,   // fragment-major [24cf][4ks][64][8]
    const float* __restrict__ gE, const float* __restrict__ bE,
    float* __restrict__ stats, float* __restrict__ rmean,
    float* __restrict__ obuf) {
  __shared__ __align__(16) ushort ed[68 * 128];   // 17.4 KB
  __shared__ float stmu[68], strs[68];
  int bn = blockIdx.x;
  int b = bn / N_;
  int tid = threadIdx.x;
  int w = tid >> 6, lane = tid & 63, lr = lane & 15, lk8 = (lane >> 4) * 8;
  int swz = (lr & 7) << 3;
  int rb = (lane >> 4) * 4;
  size_t ebase = (size_t)bn * N_ * 128;

  // stage bf16 edge tile + per-row LN stats
  for (int i = 0; i < 5; i++) {
    int u = tid + i * 256;
    if (u < 67 * 16) {
      int row = u >> 4, k8 = (u & 15) * 8;
      short8 t = __builtin_nontemporal_load(
          reinterpret_cast<const short8*>(&edge[ebase + (size_t)row * 128 + k8]));
      *reinterpret_cast<short8*>(&ed[row * 128 + (k8 ^ ((row & 7) << 3))]) = t;
      float s = 0.f, q = 0.f;
#pragma unroll
      for (int j = 0; j < 8; j++) { float v = b2f((ushort)t[j]); s += v; q += v * v; }
      for (int o = 8; o; o >>= 1) { s += __shfl_xor(s, o); q += __shfl_xor(q, o); }
      if ((u & 15) == 0) {
        float mu = s * (1.f / 128.f);
        float rs = rsqrtf(q * (1.f / 128.f) - mu * mu + 1e-5f);
        stmu[row] = mu; strs[row] = rs;
        stats[2 * (size_t)(bn * N_ + row)] = mu;
        stats[2 * (size_t)(bn * N_ + row) + 1] = rs;
      }
    }
  }
  __syncthreads();   // the only barrier
  // rowmean of LN(edge)
  if (tid < 128) {
    float s = 0.f;
    for (int m = 0; m < 67; m++)
      s += (b2f(ed[m * 128 + (tid ^ ((m & 7) << 3))]) - stmu[m]) * strs[m];
    rmean[(size_t)bn * 128 + tid] = gE[tid] * (s * (1.f / 67.f)) + bE[tid];
  }

  // each wave owns heads w and w+4 end-to-end
  for (int hh = 0; hh < 2; hh++) {
    int h = w + hh * 4;
    // E fragments for this head: q_e(cl0), k_e(cl1), v_e(cl2)
    f32x4 acc[5][3] = {};
    __builtin_amdgcn_s_setprio(1);
#pragma unroll
    for (int ks = 0; ks < 4; ks++) {
      int kof = ks * 32 + lk8;
      short8 af[5];
#pragma unroll
      for (int rf = 0; rf < 5; rf++)
        af[rf] = *reinterpret_cast<const short8*>(&ed[(rf * 16 + lr) * 128 + (kof ^ swz)]);
#pragma unroll
      for (int cl = 0; cl < 3; cl++) {
        short8 bf = *reinterpret_cast<const short8*>(
            &wqf[(size_t)(((h * 3 + cl) * 4 + ks) * 64 + lane) * 8]);
#pragma unroll
        for (int rf = 0; rf < 5; rf++)
          acc[rf][cl] = __builtin_amdgcn_mfma_f32_16x16x32_bf16(af[rf], bf, acc[rf][cl], 0, 0, 0);
      }
    }
    __builtin_amdgcn_s_setprio(0);
    // scores: per-lane product + shuffle-reduce over lr (bits 0..3)
    float qn_d = qkvn[(size_t)bn * 384 + h * 48 + lr];
    float att[5][4];
    float mx = -1e30f;
#pragma unroll
    for (int rf = 0; rf < 5; rf++) {
#pragma unroll
      for (int rg = 0; rg < 4; rg++) {
        int m = rf * 16 + rb + rg;
        float kn = (m < 67) ? qkvn[(size_t)(b * N_ + m) * 384 + h * 48 + 16 + lr] : 0.f;
        float p = (qn_d + acc[rf][0][rg]) * (kn + acc[rf][1][rg]);
        for (int o = 8; o; o >>= 1) p += __shfl_xor(p, o);
        p = (m < 67) ? p * 0.25f : -1e30f;
        att[rf][rg] = p;
        mx = fmaxf(mx, p);
      }
    }
    mx = fmaxf(mx, __shfl_xor(mx, 16));
    mx = fmaxf(mx, __shfl_xor(mx, 32));
    float ssum = 0.f;
#pragma unroll
    for (int rf = 0; rf < 5; rf++)
#pragma unroll
      for (int rg = 0; rg < 4; rg++) {
        int m = rf * 16 + rb + rg;
        float e = (m < 67) ? __expf(att[rf][rg] - mx) : 0.f;
        att[rf][rg] = e;
        ssum += e;
      }
    ssum += __shfl_xor(ssum, 16);
    ssum += __shfl_xor(ssum, 32);
    float inv = 1.f / ssum;
    // PV: per-lane over own rows, then reduce across row-groups
    float oacc = 0.f;
#pragma unroll
    for (int rf = 0; rf < 5; rf++)
#pragma unroll
      for (int rg = 0; rg < 4; rg++) {
        int m = rf * 16 + rb + rg;
        if (m < 67) {
          float vn = qkvn[(size_t)(b * N_ + m) * 384 + h * 48 + 32 + lr];
          oacc += att[rf][rg] * (vn + acc[rf][2][rg]);
        }
      }
    oacc += __shfl_xor(oacc, 16);
    oacc += __shfl_xor(oacc, 32);
    if (lane < 16) obuf[(size_t)bn * 128 + h * 16 + lr] = oacc * inv;
  }
}

// ---------------- col means of LN(edge) ----------------
__global__ void k_colmean(const ushort* __restrict__ edge, const float* __restrict__ stats,
                          const float* __restrict__ g, const float* __restrict__ bb,
                          float* __restrict__ cmean) {
  int bm = blockIdx.x;
  int b = bm / N_, m = bm - b * N_;
  int d = threadIdx.x;
  float s = 0.f;
  for (int n = 0; n < N_; n++) {
    size_t r = (size_t)b * NN_ + (size_t)n * N_ + m;
    s += (b2f(edge[r * D_ + d]) - stats[2 * r]) * stats[2 * r + 1];
  }
  cmean[(size_t)bm * D_ + d] = g[d] * (s * (1.f / 67.f)) + bb[d];
}

// ---------------- fully-fused edge block: LDS-staged frag-major weights ----------------
__global__ __launch_bounds__(256, 2) void k_fedge(
    const ushort* __restrict__ ein, ushort* __restrict__ eout,
    const float* __restrict__ stats,
    const float* __restrict__ gE, const float* __restrict__ bE,
    const ushort* __restrict__ wef,
    const float* __restrict__ rvec, const float* __restrict__ cvec,
    const ushort* __restrict__ wcef,
    const float* __restrict__ bcE,
    const float* __restrict__ gM, const float* __restrict__ bM,
    const ushort* __restrict__ w1f,
    const float* __restrict__ mb1,
    const ushort* __restrict__ w2f,
    const float* __restrict__ mb2) {
  __shared__ __align__(16) ushort As[64 * 256];
  __shared__ __align__(16) ushort mt[64 * 128];
  __shared__ __align__(16) ushort Wb[32 * 512];
  int tid = threadIdx.x;
  int r0 = blockIdx.x * 64;
  int w = tid >> 6, lane = tid & 63, lr = lane & 15, lk8 = (lane >> 4) * 8;
  int swz = (lr & 7) << 3;
  int rb = (lane >> 4) * 4;
  int arow = w * 16 + lr;

  auto stageW = [&](const ushort* src) {
#pragma unroll
    for (int i = 0; i < 8; i++) {
      int u = tid + i * 256;
      short8 t = *reinterpret_cast<const short8*>(&src[(size_t)u * 8]);
      *reinterpret_cast<short8*>(&Wb[u * 8]) = t;
    }
  };

#pragma unroll
  for (int i = 0; i < 8; i++) {
    int u = tid + i * 256;
    int row = u >> 5, c8 = (u & 31) * 8;
    int gr = r0 + row;
    int grc = (gr < RE_) ? gr : 0;
    int cc = c8 & 127;
    short8 t;
    float mu, rs;
    if (c8 < 128) {
      size_t srow = (size_t)grc;
      mu = stats[2 * srow]; rs = stats[2 * srow + 1];
      t = *reinterpret_cast<const short8*>(&ein[srow * 128 + cc]);
    } else {
      int b = grc / NN_; int rem = grc - b * NN_;
      int n = rem / N_, m = rem - n * N_;
      size_t srow = (size_t)b * NN_ + (size_t)m * N_ + n;
      mu = stats[2 * srow]; rs = stats[2 * srow + 1];
      t = __builtin_nontemporal_load(reinterpret_cast<const short8*>(&ein[srow * 128 + cc]));
    }
    short8 r8;
#pragma unroll
    for (int j = 0; j < 8; j++) {
      float v = (b2f((ushort)t[j]) - mu) * rs * gE[cc + j] + bE[cc + j];
      r8[j] = (short)f2b(v);
    }
    *reinterpret_cast<short8*>(&As[row * 256 + (c8 ^ ((row & 7) << 3))]) = r8;
  }
  int rvb[4], cvb[4], grows[4]; bool vr[4];
#pragma unroll
  for (int rg = 0; rg < 4; rg++) {
    int gr = r0 + w * 16 + rb + rg;
    vr[rg] = gr < RE_;
    int grc = vr[rg] ? gr : 0;
    grows[rg] = grc;
    int b = grc / NN_; int rem = grc - b * NN_;
    int n = rem / N_, m = rem - n * N_;
    rvb[rg] = (b * N_ + n) * 128;
    cvb[rg] = (b * N_ + m) * 128;
  }
  __syncthreads();

  for (int h = 0; h < 2; h++) {
    if (h) __syncthreads();
    stageW(wef + (size_t)h * 32 * 512);
    __syncthreads();
    f32x4 acc[4] = {};
    __builtin_amdgcn_s_setprio(1);
#pragma unroll
    for (int ks = 0; ks < 8; ks++) {
      int kof = ks * 32 + lk8;
      short8 af = *reinterpret_cast<const short8*>(&As[arow * 256 + (kof ^ swz)]);
#pragma unroll
      for (int cf = 0; cf < 4; cf++) {
        short8 bf = *reinterpret_cast<const short8*>(&Wb[(cf * 8 + ks) * 512 + lane * 8]);
        acc[cf] = __builtin_amdgcn_mfma_f32_16x16x32_bf16(af, bf, acc[cf], 0, 0, 0);
      }
    }
    __builtin_amdgcn_s_setprio(0);
#pragma unroll
    for (int cf = 0; cf < 4; cf++) {
      int c = (h * 4 + cf) * 16 + lr;
#pragma unroll
      for (int rg = 0; rg < 4; rg++) {
        float v = acc[cf][rg] + rvec[rvb[rg] + c] + cvec[cvb[rg] + c];
        int mrow = w * 16 + rb + rg;
        mt[mrow * 128 + (c ^ ((mrow & 7) << 3))] = f2b(gelu_f(v));
      }
    }
  }

  __syncthreads();
  stageW(wcef);
  __syncthreads();
  f32x4 e1[8] = {};
  __builtin_amdgcn_s_setprio(1);
#pragma unroll
  for (int ks = 0; ks < 4; ks++) {
    int kof = ks * 32 + lk8;
    short8 af = *reinterpret_cast<const short8*>(&mt[arow * 128 + (kof ^ swz)]);
#pragma unroll
    for (int cf = 0; cf < 8; cf++) {
      short8 bf = *reinterpret_cast<const short8*>(&Wb[(cf * 4 + ks) * 512 + lane * 8]);
      e1[cf] = __builtin_amdgcn_mfma_f32_16x16x32_bf16(af, bf, e1[cf], 0, 0, 0);
    }
  }
  __builtin_amdgcn_s_setprio(0);
  {
    float sr[4] = {0, 0, 0, 0}, qr[4] = {0, 0, 0, 0};
#pragma unroll
    for (int cf = 0; cf < 8; cf++) {
      int c = cf * 16 + lr;
#pragma unroll
      for (int rg = 0; rg < 4; rg++) {
        float v = e1[cf][rg] + bcE[c] + b2f(ein[(size_t)grows[rg] * 128 + c]);
        e1[cf][rg] = v;
        sr[rg] += v; qr[rg] += v * v;
      }
    }
#pragma unroll
    for (int rg = 0; rg < 4; rg++) {
      float s = sr[rg], q = qr[rg];
      for (int o = 8; o; o >>= 1) { s += __shfl_xor(s, o); q += __shfl_xor(q, o); }
      float mu = s * (1.f / 128.f);
      float rs = rsqrtf(q * (1.f / 128.f) - mu * mu + 1e-5f);
#pragma unroll
      for (int cf = 0; cf < 8; cf++) {
        int c = cf * 16 + lr;
        int mrow = w * 16 + rb + rg;
        mt[mrow * 128 + (c ^ ((mrow & 7) << 3))] =
            f2b((e1[cf][rg] - mu) * rs * gM[c] + bM[c]);
      }
    }
  }

  for (int h = 0; h < 2; h++) {
    __syncthreads();
    stageW(w1f + (size_t)h * 32 * 512);
    __syncthreads();
    f32x4 acc[8] = {};
    __builtin_amdgcn_s_setprio(1);
#pragma unroll
    for (int ks = 0; ks < 4; ks++) {
      int kof = ks * 32 + lk8;
      short8 af = *reinterpret_cast<const short8*>(&mt[arow * 128 + (kof ^ swz)]);
#pragma unroll
      for (int cf = 0; cf < 8; cf++) {
        short8 bf = *reinterpret_cast<const short8*>(&Wb[(cf * 4 + ks) * 512 + lane * 8]);
        acc[cf] = __builtin_amdgcn_mfma_f32_16x16x32_bf16(af, bf, acc[cf], 0, 0, 0);
      }
    }
    __builtin_amdgcn_s_setprio(0);
#pragma unroll
    for (int cf = 0; cf < 8; cf++) {
      int c2 = (h * 8 + cf) * 16 + lr;
#pragma unroll
      for (int rg = 0; rg < 4; rg++) {
        int mrow = w * 16 + rb + rg;
        As[mrow * 256 + (c2 ^ ((mrow & 7) << 3))] = f2b(gelu_f(acc[cf][rg] + mb1[c2]));
      }
    }
  }

  for (int h = 0; h < 2; h++) {
    __syncthreads();
    stageW(w2f + (size_t)h * 32 * 512);
    __syncthreads();
    f32x4 acc[4] = {};
    __builtin_amdgcn_s_setprio(1);
#pragma unroll
    for (int ks = 0; ks < 8; ks++) {
      int kof = ks * 32 + lk8;
      short8 af = *reinterpret_cast<const short8*>(&As[arow * 256 + (kof ^ swz)]);
#pragma unroll
      for (int cf = 0; cf < 4; cf++) {
        short8 bf = *reinterpret_cast<const short8*>(&Wb[(cf * 8 + ks) * 512 + lane * 8]);
        acc[cf] = __builtin_amdgcn_mfma_f32_16x16x32_bf16(af, bf, acc[cf], 0, 0, 0);
      }
    }
    __builtin_amdgcn_s_setprio(0);
#pragma unroll
    for (int cf = 0; cf < 4; cf++) {
      int cg = h * 4 + cf;
      int c = cg * 16 + lr;
#pragma unroll
      for (int rg = 0; rg < 4; rg++) {
        int mrow = w * 16 + rb + rg;
        mt[mrow * 128 + (c ^ ((mrow & 7) << 3))] = f2b(e1[cg][rg] + acc[cf][rg] + mb2[c]);
      }
    }
  }

  __syncthreads();
#pragma unroll
  for (int p = 0; p < 4; p++) {
    int u = p * 256 + tid;
    int row = u >> 4, col8 = (u & 15) * 8;
    int gr = r0 + row;
    if (gr < RE_) {
      short8 v = *reinterpret_cast<const short8*>(&mt[row * 128 + (col8 ^ ((row & 7) << 3))]);
      __builtin_nontemporal_store(v, reinterpret_cast<short8*>(&eout[(size_t)gr * 128 + col8]));
    }
  }
}

// ---------------- head ----------------
__global__ void k_head(const float* __restrict__ node, const float* __restrict__ Wo1,
                       const float* __restrict__ bo1, const float* __restrict__ Wo2,
                       const float* __restrict__ bo2, float* __restrict__ out) {
  int b = blockIdx.x;
  int tid = threadIdx.x;  // 128
  __shared__ float gsh[D_];
  __shared__ float h1[D_];
  float s = 0.f;
  for (int n = 0; n < N_; n++) s += node[((size_t)b * N_ + n) * D_ + tid];
  gsh[tid] = s * (1.f / 67.f);
  __syncthreads();
  float a = 0.f;
  for (int k = 0; k < D_; k++) a += gsh[k] * Wo1[k * D_ + tid];
  h1[tid] = fmaxf(a + bo1[tid], 0.f);
  __syncthreads();
  if (tid < DOUT_) {
    float r = 0.f;
    for (int k = 0; k < D_; k++) r += h1[k] * Wo2[k * DOUT_ + tid];
    out[b * DOUT_ + tid] = r + bo2[tid];
  }
}

// ---------------- host ----------------
extern "C" void kernel_launch(void* const* d_in, const int* in_sizes, int n_in,
                              void* d_out, int out_size, void* d_ws, size_t ws_size,
                              hipStream_t stream) {
  const float* w0   = (const float*)d_in[0];
  const float* w1   = (const float*)d_in[1];
  const float* w2   = (const float*)d_in[2];
  const float* b0   = (const float*)d_in[3];
  const float* b1   = (const float*)d_in[4];
  const float* b2   = (const float*)d_in[5];
  const float* pwW  = (const float*)d_in[6];
  const float* pwb  = (const float*)d_in[7];
  const float* pbW  = (const float*)d_in[8];
  const float* pbb  = (const float*)d_in[9];
  const float* niW  = (const float*)d_in[10];
  const float* nib  = (const float*)d_in[11];
  const float* eiW  = (const float*)d_in[12];
  const float* eib  = (const float*)d_in[13];
  const float* pos  = (const float*)d_in[14];
  const float* alng = (const float*)d_in[15];
  const float* alnb = (const float*)d_in[16];
  const float* Wqkvn= (const float*)d_in[17];
  const float* Wqkve= (const float*)d_in[18];
  const float* Wao  = (const float*)d_in[19];
  const float* bao  = (const float*)d_in[20];
  const float* Wl0  = (const float*)d_in[21];
  const float* bl0  = (const float*)d_in[22];
  const float* nlng = (const float*)d_in[23];
  const float* nlnb = (const float*)d_in[24];
  const float* nW1  = (const float*)d_in[25];
  const float* nb1  = (const float*)d_in[26];
  const float* nW2  = (const float*)d_in[27];
  const float* nb2  = (const float*)d_in[28];
  const float* elng = (const float*)d_in[29];
  const float* elnb = (const float*)d_in[30];
  const float* We   = (const float*)d_in[31];
  const float* be   = (const float*)d_in[32];
  const float* Ws   = (const float*)d_in[33];
  const float* bs   = (const float*)d_in[34];
  const float* Wt   = (const float*)d_in[35];
  const float* bt   = (const float*)d_in[36];
  const float* Wer  = (const float*)d_in[37];
  const float* Wec  = (const float*)d_in[38];
  const float* We1  = (const float*)d_in[39];
  const float* be1  = (const float*)d_in[40];
  const float* Wel0 = (const float*)d_in[41];
  const float* bel0 = (const float*)d_in[42];
  const float* mlng = (const float*)d_in[43];
  const float* mlnb = (const float*)d_in[44];
  const float* mW1  = (const float*)d_in[45];
  const float* mb1  = (const float*)d_in[46];
  const float* mW2  = (const float*)d_in[47];
  const float* mb2  = (const float*)d_in[48];
  const float* Wo1  = (const float*)d_in[49];
  const float* bo1  = (const float*)d_in[50];
  const float* Wo2  = (const float*)d_in[51];
  const float* bo2  = (const float*)d_in[52];
  float* outp = (float*)d_out;

  const size_t E = (size_t)RE_ * D_;
  const size_t NODE = (size_t)RN_ * D_;
  const int DD = D_ * D_;

  float* ws = (float*)d_ws;
  size_t off = 0;
  auto alloc = [&](size_t nf) { float* p = ws + off; off += nf; return p; };
  ushort* edgeA = (ushort*)alloc(E / 2);
  ushort* edgeB = (ushort*)alloc(E / 2);
  float* stats = alloc(2 * (size_t)RE_);
  float* node  = alloc(NODE);
  float* qkvn  = alloc(3 * NODE);
  float* obuf  = alloc(NODE);
  float* rmean = alloc(NODE);
  float* cmean = alloc(NODE);
  float* rvec  = alloc(NODE);
  float* cvec  = alloc(NODE);
  float* WcN   = alloc((size_t)L_ * DD);
  float* bcN   = alloc((size_t)L_ * D_);
  float* WcE   = alloc((size_t)L_ * DD);
  float* bcE   = alloc((size_t)L_ * D_);
  float* vecs  = alloc(4 * D_);
  ushort* wbf   = (ushort*)alloc(245760);
  ushort* wq_fm = wbf;
  ushort* we_fm = wq_fm + (size_t)L_ * 49152;
  ushort* wce_fm= we_fm + (size_t)L_ * 32768;
  ushort* w1_fm = wce_fm + (size_t)L_ * 16384;
  ushort* w2_fm = w1_fm + (size_t)L_ * 32768;
  (void)ws_size; (void)in_sizes; (void)n_in; (void)out_size;

  k_comb<<<(2 * L_ * DD + 255) / 256, 256, 0, stream>>>(Wao, bao, Wl0, bl0, We1, be1, Wel0, bel0,
                                                        WcN, bcN, WcE, bcE);
  k_prepw<<<1920, 256, 0, stream>>>(Wqkve, We, WcE, mW1, mW2, wq_fm, we_fm, wce_fm, w1_fm, w2_fm);
  k_vecs<<<1, 128, 0, stream>>>(pbW, pbb, niW, nib, pwW, pwb, eiW, eib, vecs);
  k_init_node<<<(RN_ * D_ + 255) / 256, 256, 0, stream>>>(b0, b1, b2, vecs, pos, node);
  k_init_edge<<<(int)((E + 255) / 256), 256, 0, stream>>>(w0, w1, w2, vecs, edgeA);

  const int GE = (RE_ + 63) / 64;  // 2245
  const int GN = (RN_ + 63) / 64;  // 34
  const int GM = RN_ / 16;         // 134

  for (int l = 0; l < L_; l++) {
    ushort* ein  = (l & 1) ? edgeB : edgeA;
    ushort* eout = (l & 1) ? edgeA : edgeB;
    const float* Wqn = Wqkvn + (size_t)l * D_ * 384;

    k_lnqkv<<<dim3(GN, 6), 256, 0, stream>>>(node, alng + l * D_, alnb + l * D_, Wqn, qkvn);
    k_eattn<<<RN_, 256, 0, stream>>>(ein, qkvn, wq_fm + (size_t)l * 49152,
                                     elng + l * D_, elnb + l * D_, stats, rmean, obuf);
    k_nodemlp<<<GM, 256, 0, stream>>>(node, obuf, WcN + (size_t)l * DD, bcN + l * D_,
                                      nlng + l * D_, nlnb + l * D_,
                                      nW1 + (size_t)l * D_ * 256, nb1 + l * 256,
                                      nW2 + (size_t)l * 256 * D_, nb2 + l * D_);

    k_colmean<<<RN_, 128, 0, stream>>>(ein, stats, elng + l * D_, elnb + l * D_, cmean);
    k_nvec<<<dim3(GN, 2, 2), 256, 0, stream>>>(node, rmean, cmean,
                                               Ws + (size_t)l * DD, Wer + (size_t)l * DD,
                                               Wt + (size_t)l * DD, Wec + (size_t)l * DD,
                                               bs + l * D_, be + l * D_, bt + l * D_,
                                               rvec, cvec);

    k_fedge<<<GE, 256, 0, stream>>>(ein, eout, stats,
                                    elng + l * D_, elnb + l * D_,
                                    we_fm + (size_t)l * 32768, rvec, cvec,
                                    wce_fm + (size_t)l * 16384, bcE + l * D_,
                                    mlng + l * D_, mlnb + l * D_,
                                    w1_fm + (size_t)l * 32768, mb1 + l * 256,
                                    w2_fm + (size_t)l * 32768, mb2 + l * D_);
  }

  k_head<<<B_, 128, 0, stream>>>(node, Wo1, bo1, Wo2, bo2, outp);
}

// Round 14
// 1165.144 us; speedup vs baseline: 1.1194x; 1.1194x over previous
//
#include <hip/hip_runtime.h>
#include <math.h>

constexpr int B_ = 32, N_ = 67, D_ = 128, H_ = 8, DH_ = 16, L_ = 3;
constexpr int NN_ = N_ * N_;          // 4489
constexpr int RN_ = B_ * N_;          // 2144
constexpr int RE_ = B_ * NN_;         // 143648
constexpr int DOUT_ = 10;

typedef __attribute__((ext_vector_type(8))) short short8;
typedef __attribute__((ext_vector_type(4))) float f32x4;

// branchless tanh-approx GELU
__device__ __forceinline__ float gelu_f(float x) {
  float u = x * (0.7978845608028654f + 0.035677408136f * x * x);
  float e = __expf(-2.f * u);
  return x * (1.f / (1.f + e));
}
__device__ __forceinline__ ushort f2b(float x) {
  union { float f; unsigned u; } v; v.f = x;
  return (ushort)((v.u + 0x7FFFu + ((v.u >> 16) & 1u)) >> 16);
}
__device__ __forceinline__ float b2f(ushort u) {
  union { unsigned u; float f; } v; v.u = (unsigned)u << 16; return v.f;
}

// ---------------- precompute: combined weights (Wao@Wl0, We1@Wel0) ----------------
__global__ void k_comb(const float* __restrict__ Wao, const float* __restrict__ bao,
                       const float* __restrict__ Wl0, const float* __restrict__ bl0,
                       const float* __restrict__ We1, const float* __restrict__ be1,
                       const float* __restrict__ Wel0, const float* __restrict__ bel0,
                       float* WcN, float* bcN, float* WcE, float* bcE) {
  int t = blockIdx.x * blockDim.x + threadIdx.x;
  const int half = L_ * D_ * D_;
  if (t >= 2 * half) return;
  int which = t / half;
  int u = t - which * half;
  int l = u / (D_ * D_);
  int ij = u - l * (D_ * D_);
  int i = ij >> 7, j = ij & 127;
  const float* A  = (which == 0 ? Wao : We1) + (size_t)l * D_ * D_;
  const float* Bm = (which == 0 ? Wl0 : Wel0) + (size_t)l * D_ * D_;
  float s = 0.f;
  for (int k = 0; k < D_; k++) s += A[i * D_ + k] * Bm[k * D_ + j];
  if (which == 0) WcN[u] = s; else WcE[u] = s;
  if (i == 0) {
    const float* ba = (which == 0 ? bao : be1) + l * D_;
    const float* bl = (which == 0 ? bl0 : bel0) + l * D_;
    float sb = 0.f;
    for (int k = 0; k < D_; k++) sb += ba[k] * Bm[k * D_ + j];
    if (which == 0) bcN[l * D_ + j] = sb + bl[j]; else bcE[l * D_ + j] = sb + bl[j];
  }
}

// ---------------- precompute: fragment-major bf16 weights ----------------
__device__ __forceinline__ float enc_src(const float* src, int K, int C, int NKS, int r, int l) {
  int frag = r >> 9;
  int within = r & 511;
  int lane = within >> 3, j = within & 7;
  int cf = frag / NKS, ks = frag - cf * NKS;
  int k = ks * 32 + (lane >> 4) * 8 + j;
  int c = cf * 16 + (lane & 15);
  return src[(size_t)l * K * C + (size_t)k * C + c];
}

__global__ void k_prepw(const float* __restrict__ Wqkve, const float* __restrict__ We,
                        const float* __restrict__ WcE, const float* __restrict__ mW1,
                        const float* __restrict__ mW2,
                        ushort* wq, ushort* we, ushort* wce, ushort* w1, ushort* w2) {
  int t = blockIdx.x * 256 + threadIdx.x;
  const int S0 = L_ * 49152, S1 = L_ * 32768, S2 = L_ * 16384, S3 = L_ * 32768, S4 = L_ * 32768;
  if (t < S0) { int l = t / 49152, r = t % 49152; wq[t]  = f2b(enc_src(Wqkve, 128, 384, 4, r, l)); return; }
  t -= S0;
  if (t < S1) { int l = t / 32768, r = t % 32768; we[t]  = f2b(enc_src(We,   256, 128, 8, r, l)); return; }
  t -= S1;
  if (t < S2) { int l = t / 16384, r = t % 16384; wce[t] = f2b(enc_src(WcE,  128, 128, 4, r, l)); return; }
  t -= S2;
  if (t < S3) { int l = t / 32768, r = t % 32768; w1[t]  = f2b(enc_src(mW1,  128, 256, 4, r, l)); return; }
  t -= S3;
  if (t < S4) { int l = t / 32768, r = t % 32768; w2[t]  = f2b(enc_src(mW2,  256, 128, 8, r, l)); return; }
}

// ---------------- precompute: folded input-embed vectors ----------------
__global__ void k_vecs(const float* pbW, const float* pbb, const float* niW, const float* nib,
                       const float* pwW, const float* pwb, const float* eiW, const float* eib,
                       float* vecs) {
  int j = threadIdx.x;
  if (j >= D_) return;
  float u = 0, c = 0, v = 0, ce = 0;
  for (int k = 0; k < D_; k++) {
    u  += pbW[k] * niW[k * D_ + j];
    c  += pbb[k] * niW[k * D_ + j];
    v  += pwW[k] * eiW[k * D_ + j];
    ce += pwb[k] * eiW[k * D_ + j];
  }
  vecs[j] = u; vecs[D_ + j] = c + nib[j]; vecs[2 * D_ + j] = v; vecs[3 * D_ + j] = ce + eib[j];
}

// ---------------- init node / edge ----------------
__global__ void k_init_node(const float* __restrict__ b0, const float* __restrict__ b1,
                            const float* __restrict__ b2, const float* __restrict__ vecs,
                            const float* __restrict__ pos, float* __restrict__ node) {
  int idx = blockIdx.x * blockDim.x + threadIdx.x;
  if (idx >= RN_ * D_) return;
  int r = idx >> 7, d = idx & 127;
  int b = r / N_, n = r - b * N_;
  float nf = 0.f;
  if (n >= 2 && n < 34)       nf = b0[b * 32 + n - 2];
  else if (n >= 34 && n < 66) nf = b1[b * 32 + n - 34];
  else if (n == 66)           nf = b2[b];
  int pr = (n == 0) ? 0 : (n == 1) ? 1 : (n < 34) ? 2 : (n < 66) ? 3 : 4;
  node[idx] = nf * vecs[d] + vecs[D_ + d] + pos[pr * D_ + d];
}

__global__ void k_init_edge(const float* __restrict__ w0, const float* __restrict__ w1,
                            const float* __restrict__ w2, const float* __restrict__ vecs,
                            ushort* __restrict__ edge) {
  int idx = blockIdx.x * blockDim.x + threadIdx.x;
  if (idx >= RE_ * D_) return;
  int r = idx >> 7, d = idx & 127;
  int b = r / NN_;
  int rem = r - b * NN_;
  int n = rem / N_, m = rem - n * N_;
  float ef = 0.f;
  if (n < 2)        { if (m >= 2 && m < 34)  ef = w0[(b * 2 + n) * 32 + (m - 2)]; }
  else if (n < 34)  { if (m >= 34 && m < 66) ef = w1[(b * 32 + (n - 2)) * 32 + (m - 34)]; }
  else if (n < 66)  { if (m == 66)           ef = w2[b * 32 + (n - 34)]; }
  edge[idx] = f2b(ef * vecs[2 * D_ + d] + vecs[3 * D_ + d]);
}

// ---------------- fused node LN + QKV projection (no bias) ----------------
__global__ __launch_bounds__(256) void k_lnqkv(
    const float* __restrict__ node, const float* __restrict__ g, const float* __restrict__ bb,
    const float* __restrict__ W, float* __restrict__ out) {
  __shared__ float As[16][68];
  __shared__ float Wsh[16][68];
  __shared__ float stmu[64], strs[64];
  int r0 = blockIdx.x * 64, c0 = blockIdx.y * 64;
  int tid = threadIdx.x;
  {
    int row = tid >> 2, part = tid & 3;
    int gr = r0 + row;
    int grc = (gr < RN_) ? gr : 0;
    const float* x = node + (size_t)grc * 128 + part * 32;
    float s = 0.f, q = 0.f;
#pragma unroll
    for (int i = 0; i < 8; i++) {
      float4 v = *reinterpret_cast<const float4*>(&x[i * 4]);
      s += v.x + v.y + v.z + v.w;
      q += v.x * v.x + v.y * v.y + v.z * v.z + v.w * v.w;
    }
    for (int o = 1; o < 4; o <<= 1) { s += __shfl_xor(s, o); q += __shfl_xor(q, o); }
    if (part == 0) {
      float mu = s * (1.f / 128.f);
      stmu[row] = mu;
      strs[row] = rsqrtf(q * (1.f / 128.f) - mu * mu + 1e-5f);
    }
  }
  __syncthreads();
  int tr = tid >> 4, tc = tid & 15;
  float acc[4][4] = {};
  for (int kk = 0; kk < 128; kk += 16) {
#pragma unroll
    for (int i = 0; i < 4; i++) {
      int lin = tid + i * 256;
      int r_in = lin >> 4, k_in = lin & 15;
      int r = r0 + r_in;
      float v = 0.f;
      if (r < RN_) {
        int k = kk + k_in;
        v = (node[(size_t)r * 128 + k] - stmu[r_in]) * strs[r_in] * g[k] + bb[k];
      }
      As[k_in][r_in] = v;
    }
#pragma unroll
    for (int i = 0; i < 4; i++) {
      int lin = tid + i * 256;
      int k_in = lin >> 6, c_in = lin & 63;
      Wsh[k_in][c_in] = W[(size_t)(kk + k_in) * 384 + c0 + c_in];
    }
    __syncthreads();
#pragma unroll
    for (int k = 0; k < 16; k++) {
      float4 a4 = *reinterpret_cast<const float4*>(&As[k][tr * 4]);
      float4 b4 = *reinterpret_cast<const float4*>(&Wsh[k][tc * 4]);
      float av[4] = {a4.x, a4.y, a4.z, a4.w};
      float bv[4] = {b4.x, b4.y, b4.z, b4.w};
#pragma unroll
      for (int i = 0; i < 4; i++)
#pragma unroll
        for (int j = 0; j < 4; j++) acc[i][j] += av[i] * bv[j];
    }
    __syncthreads();
  }
#pragma unroll
  for (int i = 0; i < 4; i++) {
    int r = r0 + tr * 4 + i;
    if (r >= RN_) continue;
#pragma unroll
    for (int j = 0; j < 4; j++) {
      int c = c0 + tc * 4 + j;
      out[(size_t)r * 384 + c] = acc[i][j];
    }
  }
}

// ---------------- fused node residual + MLP ----------------
__global__ __launch_bounds__(256) void k_nodemlp(
    float* __restrict__ node, const float* __restrict__ obuf,
    const float* __restrict__ WcN, const float* __restrict__ bcN,
    const float* __restrict__ g, const float* __restrict__ bb,
    const float* __restrict__ nW1, const float* __restrict__ nb1,
    const float* __restrict__ nW2, const float* __restrict__ nb2) {
  __shared__ float As[16][17];
  __shared__ float Wsh[16][132];
  __shared__ ushort Hs[16][136];
  __shared__ ushort Ts[16][264];
  int r0 = blockIdx.x * 16;
  int tid = threadIdx.x;
  int tr = tid >> 4, tc = tid & 15;
  size_t grow = (size_t)(r0 + tr) * 128;

  auto stageW = [&](const float* src, int ld, int kk, int cbase) {
    int k = tid & 15, cp = tid >> 4;
    const float* s = &src[(size_t)(kk + k) * ld + cbase + cp * 8];
    float* d = &Wsh[k][cp * 8];
#pragma unroll
    for (int j = 0; j < 8; j++) d[j] = s[j];
  };

  float acc[8] = {};
  for (int kk = 0; kk < 128; kk += 16) {
    As[tr][tc] = obuf[grow + kk + tc];
    stageW(WcN, 128, kk, 0);
    __syncthreads();
#pragma unroll
    for (int k = 0; k < 16; k++) {
      float a = As[tr][k];
#pragma unroll
      for (int j = 0; j < 8; j++) acc[j] += a * Wsh[k][tc * 8 + j];
    }
    __syncthreads();
  }
  float nd[8];
  float s = 0.f, q = 0.f;
#pragma unroll
  for (int j = 0; j < 8; j++) {
    int c = tc * 8 + j;
    float v = node[grow + c] + acc[j] + bcN[c];
    nd[j] = v; s += v; q += v * v;
  }
  for (int o = 1; o < 16; o <<= 1) { s += __shfl_xor(s, o); q += __shfl_xor(q, o); }
  float mu = s * (1.f / 128.f);
  float rs = rsqrtf(q * (1.f / 128.f) - mu * mu + 1e-5f);
#pragma unroll
  for (int j = 0; j < 8; j++) {
    int c = tc * 8 + j;
    Hs[tr][c] = f2b((nd[j] - mu) * rs * g[c] + bb[c]);
  }
  for (int ch = 0; ch < 2; ch++) {
    float a2[8] = {};
    for (int kk = 0; kk < 128; kk += 16) {
      __syncthreads();
      stageW(nW1, 256, kk, ch * 128);
      __syncthreads();
#pragma unroll
      for (int k = 0; k < 16; k++) {
        float a = b2f(Hs[tr][kk + k]);
#pragma unroll
        for (int j = 0; j < 8; j++) a2[j] += a * Wsh[k][tc * 8 + j];
      }
    }
#pragma unroll
    for (int j = 0; j < 8; j++) {
      int c = ch * 128 + tc * 8 + j;
      Ts[tr][c] = f2b(gelu_f(a2[j] + nb1[c]));
    }
  }
  float a3[8] = {};
  for (int kk = 0; kk < 256; kk += 16) {
    __syncthreads();
    stageW(nW2, 128, kk, 0);
    __syncthreads();
#pragma unroll
    for (int k = 0; k < 16; k++) {
      float a = b2f(Ts[tr][kk + k]);
#pragma unroll
      for (int j = 0; j < 8; j++) a3[j] += a * Wsh[k][tc * 8 + j];
    }
  }
#pragma unroll
  for (int j = 0; j < 8; j++) {
    int c = tc * 8 + j;
    node[grow + c] = nd[j] + a3[j] + nb2[c];
  }
}

// ---------------- fused rvec/cvec ----------------
__global__ __launch_bounds__(256) void k_nvec(
    const float* __restrict__ node, const float* __restrict__ rmean, const float* __restrict__ cmean,
    const float* __restrict__ Ws, const float* __restrict__ Wer,
    const float* __restrict__ Wt, const float* __restrict__ Wec,
    const float* __restrict__ bs, const float* __restrict__ be, const float* __restrict__ bt,
    float* __restrict__ rvec, float* __restrict__ cvec) {
  __shared__ float Ash[16][68];
  __shared__ float Wsh[16][68];
  int which = blockIdx.z;
  const float* A2 = which ? cmean : rmean;
  const float* W1 = which ? Wt : Ws;
  const float* W2 = which ? Wec : Wer;
  float* out = which ? cvec : rvec;
  int r0 = blockIdx.x * 64, c0 = blockIdx.y * 64;
  int tid = threadIdx.x, tr = tid >> 4, tc = tid & 15;
  float acc[4][4] = {};
  for (int kk = 0; kk < 256; kk += 16) {
#pragma unroll
    for (int i = 0; i < 4; i++) {
      int lin = tid + i * 256;
      int r_in = lin >> 4, k_in = lin & 15;
      int r = r0 + r_in, k = kk + k_in;
      float v = 0.f;
      if (r < RN_) v = (k < 128) ? node[(size_t)r * 128 + k] : A2[(size_t)r * 128 + (k - 128)];
      Ash[k_in][r_in] = v;
    }
#pragma unroll
    for (int i = 0; i < 4; i++) {
      int lin = tid + i * 256;
      int k_in = lin >> 6, c_in = lin & 63;
      int k = kk + k_in, c = c0 + c_in;
      Wsh[k_in][c_in] = (k < 128) ? W1[(size_t)k * 128 + c] : W2[(size_t)(k - 128) * 128 + c];
    }
    __syncthreads();
#pragma unroll
    for (int k = 0; k < 16; k++) {
      float4 a4 = *reinterpret_cast<const float4*>(&Ash[k][tr * 4]);
      float4 b4 = *reinterpret_cast<const float4*>(&Wsh[k][tc * 4]);
      float av[4] = {a4.x, a4.y, a4.z, a4.w};
      float bv[4] = {b4.x, b4.y, b4.z, b4.w};
#pragma unroll
      for (int i = 0; i < 4; i++)
#pragma unroll
        for (int j = 0; j < 4; j++) acc[i][j] += av[i] * bv[j];
    }
    __syncthreads();
  }
#pragma unroll
  for (int i = 0; i < 4; i++) {
    int r = r0 + tr * 4 + i;
    if (r >= RN_) continue;
#pragma unroll
    for (int j = 0; j < 4; j++) {
      int c = c0 + tc * 4 + j;
      float bias = which ? bt[c] : (bs[c] + be[c]);
      out[(size_t)r * 128 + c] = acc[i][j] + bias;
    }
  }
}

// ---------------- fused per-(b,n) attention: wave-owned heads, 1 barrier ----------------
__global__ __launch_bounds__(256) void k_eattn(
    const ushort* __restrict__ edge, const float* __restrict__ qkvn,
    const ushort* __restrict__ wqf,   // fragment-major [24cf][4ks][64][8]
    const float* __restrict__ gE, const float* __restrict__ bE,
    float* __restrict__ stats, float* __restrict__ rmean,
    float* __restrict__ obuf) {
  __shared__ __align__(16) ushort ed[68 * 128];   // 17.4 KB
  __shared__ float stmu[68], strs[68];
  int bn = blockIdx.x;
  int b = bn / N_;
  int tid = threadIdx.x;
  int w = tid >> 6, lane = tid & 63, lr = lane & 15, lk8 = (lane >> 4) * 8;
  int swz = (lr & 7) << 3;
  int rb = (lane >> 4) * 4;
  size_t ebase = (size_t)bn * N_ * 128;

  // stage bf16 edge tile + per-row LN stats
  for (int i = 0; i < 5; i++) {
    int u = tid + i * 256;
    if (u < 67 * 16) {
      int row = u >> 4, k8 = (u & 15) * 8;
      short8 t = __builtin_nontemporal_load(
          reinterpret_cast<const short8*>(&edge[ebase + (size_t)row * 128 + k8]));
      *reinterpret_cast<short8*>(&ed[row * 128 + (k8 ^ ((row & 7) << 3))]) = t;
      float s = 0.f, q = 0.f;
#pragma unroll
      for (int j = 0; j < 8; j++) { float v = b2f((ushort)t[j]); s += v; q += v * v; }
      for (int o = 8; o; o >>= 1) { s += __shfl_xor(s, o); q += __shfl_xor(q, o); }
      if ((u & 15) == 0) {
        float mu = s * (1.f / 128.f);
        float rs = rsqrtf(q * (1.f / 128.f) - mu * mu + 1e-5f);
        stmu[row] = mu; strs[row] = rs;
        stats[2 * (size_t)(bn * N_ + row)] = mu;
        stats[2 * (size_t)(bn * N_ + row) + 1] = rs;
      }
    }
  }
  __syncthreads();   // the only barrier
  // rowmean of LN(edge)
  if (tid < 128) {
    float s = 0.f;
    for (int m = 0; m < 67; m++)
      s += (b2f(ed[m * 128 + (tid ^ ((m & 7) << 3))]) - stmu[m]) * strs[m];
    rmean[(size_t)bn * 128 + tid] = gE[tid] * (s * (1.f / 67.f)) + bE[tid];
  }

  // each wave owns heads w and w+4 end-to-end
  for (int hh = 0; hh < 2; hh++) {
    int h = w + hh * 4;
    f32x4 acc[5][3] = {};
    __builtin_amdgcn_s_setprio(1);
#pragma unroll
    for (int ks = 0; ks < 4; ks++) {
      int kof = ks * 32 + lk8;
      short8 af[5];
#pragma unroll
      for (int rf = 0; rf < 5; rf++)
        af[rf] = *reinterpret_cast<const short8*>(&ed[(rf * 16 + lr) * 128 + (kof ^ swz)]);
#pragma unroll
      for (int cl = 0; cl < 3; cl++) {
        short8 bf = *reinterpret_cast<const short8*>(
            &wqf[(size_t)(((h * 3 + cl) * 4 + ks) * 64 + lane) * 8]);
#pragma unroll
        for (int rf = 0; rf < 5; rf++)
          acc[rf][cl] = __builtin_amdgcn_mfma_f32_16x16x32_bf16(af[rf], bf, acc[rf][cl], 0, 0, 0);
      }
    }
    __builtin_amdgcn_s_setprio(0);
    // scores: per-lane product + shuffle-reduce over lr (bits 0..3)
    float qn_d = qkvn[(size_t)bn * 384 + h * 48 + lr];
    float att[5][4];
    float mx = -1e30f;
#pragma unroll
    for (int rf = 0; rf < 5; rf++) {
#pragma unroll
      for (int rg = 0; rg < 4; rg++) {
        int m = rf * 16 + rb + rg;
        float kn = (m < 67) ? qkvn[(size_t)(b * N_ + m) * 384 + h * 48 + 16 + lr] : 0.f;
        float p = (qn_d + acc[rf][0][rg]) * (kn + acc[rf][1][rg]);
        for (int o = 8; o; o >>= 1) p += __shfl_xor(p, o);
        p = (m < 67) ? p * 0.25f : -1e30f;
        att[rf][rg] = p;
        mx = fmaxf(mx, p);
      }
    }
    mx = fmaxf(mx, __shfl_xor(mx, 16));
    mx = fmaxf(mx, __shfl_xor(mx, 32));
    float ssum = 0.f;
#pragma unroll
    for (int rf = 0; rf < 5; rf++)
#pragma unroll
      for (int rg = 0; rg < 4; rg++) {
        int m = rf * 16 + rb + rg;
        float e = (m < 67) ? __expf(att[rf][rg] - mx) : 0.f;
        att[rf][rg] = e;
        ssum += e;
      }
    ssum += __shfl_xor(ssum, 16);
    ssum += __shfl_xor(ssum, 32);
    float inv = 1.f / ssum;
    // PV
    float oacc = 0.f;
#pragma unroll
    for (int rf = 0; rf < 5; rf++)
#pragma unroll
      for (int rg = 0; rg < 4; rg++) {
        int m = rf * 16 + rb + rg;
        if (m < 67) {
          float vn = qkvn[(size_t)(b * N_ + m) * 384 + h * 48 + 32 + lr];
          oacc += att[rf][rg] * (vn + acc[rf][2][rg]);
        }
      }
    oacc += __shfl_xor(oacc, 16);
    oacc += __shfl_xor(oacc, 32);
    if (lane < 16) obuf[(size_t)bn * 128 + h * 16 + lr] = oacc * inv;
  }
}

// ---------------- col means of LN(edge) ----------------
__global__ void k_colmean(const ushort* __restrict__ edge, const float* __restrict__ stats,
                          const float* __restrict__ g, const float* __restrict__ bb,
                          float* __restrict__ cmean) {
  int bm = blockIdx.x;
  int b = bm / N_, m = bm - b * N_;
  int d = threadIdx.x;
  float s = 0.f;
  for (int n = 0; n < N_; n++) {
    size_t r = (size_t)b * NN_ + (size_t)n * N_ + m;
    s += (b2f(edge[r * D_ + d]) - stats[2 * r]) * stats[2 * r + 1];
  }
  cmean[(size_t)bm * D_ + d] = g[d] * (s * (1.f / 67.f)) + bb[d];
}

// ---------------- fully-fused edge block: LDS-staged frag-major weights ----------------
__global__ __launch_bounds__(256, 2) void k_fedge(
    const ushort* __restrict__ ein, ushort* __restrict__ eout,
    const float* __restrict__ stats,
    const float* __restrict__ gE, const float* __restrict__ bE,
    const ushort* __restrict__ wef,
    const float* __restrict__ rvec, const float* __restrict__ cvec,
    const ushort* __restrict__ wcef,
    const float* __restrict__ bcE,
    const float* __restrict__ gM, const float* __restrict__ bM,
    const ushort* __restrict__ w1f,
    const float* __restrict__ mb1,
    const ushort* __restrict__ w2f,
    const float* __restrict__ mb2) {
  __shared__ __align__(16) ushort As[64 * 256];
  __shared__ __align__(16) ushort mt[64 * 128];
  __shared__ __align__(16) ushort Wb[32 * 512];
  int tid = threadIdx.x;
  int r0 = blockIdx.x * 64;
  int w = tid >> 6, lane = tid & 63, lr = lane & 15, lk8 = (lane >> 4) * 8;
  int swz = (lr & 7) << 3;
  int rb = (lane >> 4) * 4;
  int arow = w * 16 + lr;

  auto stageW = [&](const ushort* src) {
#pragma unroll
    for (int i = 0; i < 8; i++) {
      int u = tid + i * 256;
      short8 t = *reinterpret_cast<const short8*>(&src[(size_t)u * 8]);
      *reinterpret_cast<short8*>(&Wb[u * 8]) = t;
    }
  };

#pragma unroll
  for (int i = 0; i < 8; i++) {
    int u = tid + i * 256;
    int row = u >> 5, c8 = (u & 31) * 8;
    int gr = r0 + row;
    int grc = (gr < RE_) ? gr : 0;
    int cc = c8 & 127;
    short8 t;
    float mu, rs;
    if (c8 < 128) {
      size_t srow = (size_t)grc;
      mu = stats[2 * srow]; rs = stats[2 * srow + 1];
      t = *reinterpret_cast<const short8*>(&ein[srow * 128 + cc]);
    } else {
      int b = grc / NN_; int rem = grc - b * NN_;
      int n = rem / N_, m = rem - n * N_;
      size_t srow = (size_t)b * NN_ + (size_t)m * N_ + n;
      mu = stats[2 * srow]; rs = stats[2 * srow + 1];
      t = __builtin_nontemporal_load(reinterpret_cast<const short8*>(&ein[srow * 128 + cc]));
    }
    short8 r8;
#pragma unroll
    for (int j = 0; j < 8; j++) {
      float v = (b2f((ushort)t[j]) - mu) * rs * gE[cc + j] + bE[cc + j];
      r8[j] = (short)f2b(v);
    }
    *reinterpret_cast<short8*>(&As[row * 256 + (c8 ^ ((row & 7) << 3))]) = r8;
  }
  int rvb[4], cvb[4], grows[4]; bool vr[4];
#pragma unroll
  for (int rg = 0; rg < 4; rg++) {
    int gr = r0 + w * 16 + rb + rg;
    vr[rg] = gr < RE_;
    int grc = vr[rg] ? gr : 0;
    grows[rg] = grc;
    int b = grc / NN_; int rem = grc - b * NN_;
    int n = rem / N_, m = rem - n * N_;
    rvb[rg] = (b * N_ + n) * 128;
    cvb[rg] = (b * N_ + m) * 128;
  }
  __syncthreads();

  for (int h = 0; h < 2; h++) {
    if (h) __syncthreads();
    stageW(wef + (size_t)h * 32 * 512);
    __syncthreads();
    f32x4 acc[4] = {};
    __builtin_amdgcn_s_setprio(1);
#pragma unroll
    for (int ks = 0; ks < 8; ks++) {
      int kof = ks * 32 + lk8;
      short8 af = *reinterpret_cast<const short8*>(&As[arow * 256 + (kof ^ swz)]);
#pragma unroll
      for (int cf = 0; cf < 4; cf++) {
        short8 bf = *reinterpret_cast<const short8*>(&Wb[(cf * 8 + ks) * 512 + lane * 8]);
        acc[cf] = __builtin_amdgcn_mfma_f32_16x16x32_bf16(af, bf, acc[cf], 0, 0, 0);
      }
    }
    __builtin_amdgcn_s_setprio(0);
#pragma unroll
    for (int cf = 0; cf < 4; cf++) {
      int c = (h * 4 + cf) * 16 + lr;
#pragma unroll
      for (int rg = 0; rg < 4; rg++) {
        float v = acc[cf][rg] + rvec[rvb[rg] + c] + cvec[cvb[rg] + c];
        int mrow = w * 16 + rb + rg;
        mt[mrow * 128 + (c ^ ((mrow & 7) << 3))] = f2b(gelu_f(v));
      }
    }
  }

  __syncthreads();
  stageW(wcef);
  __syncthreads();
  f32x4 e1[8] = {};
  __builtin_amdgcn_s_setprio(1);
#pragma unroll
  for (int ks = 0; ks < 4; ks++) {
    int kof = ks * 32 + lk8;
    short8 af = *reinterpret_cast<const short8*>(&mt[arow * 128 + (kof ^ swz)]);
#pragma unroll
    for (int cf = 0; cf < 8; cf++) {
      short8 bf = *reinterpret_cast<const short8*>(&Wb[(cf * 4 + ks) * 512 + lane * 8]);
      e1[cf] = __builtin_amdgcn_mfma_f32_16x16x32_bf16(af, bf, e1[cf], 0, 0, 0);
    }
  }
  __builtin_amdgcn_s_setprio(0);
  {
    float sr[4] = {0, 0, 0, 0}, qr[4] = {0, 0, 0, 0};
#pragma unroll
    for (int cf = 0; cf < 8; cf++) {
      int c = cf * 16 + lr;
#pragma unroll
      for (int rg = 0; rg < 4; rg++) {
        float v = e1[cf][rg] + bcE[c] + b2f(ein[(size_t)grows[rg] * 128 + c]);
        e1[cf][rg] = v;
        sr[rg] += v; qr[rg] += v * v;
      }
    }
#pragma unroll
    for (int rg = 0; rg < 4; rg++) {
      float s = sr[rg], q = qr[rg];
      for (int o = 8; o; o >>= 1) { s += __shfl_xor(s, o); q += __shfl_xor(q, o); }
      float mu = s * (1.f / 128.f);
      float rs = rsqrtf(q * (1.f / 128.f) - mu * mu + 1e-5f);
#pragma unroll
      for (int cf = 0; cf < 8; cf++) {
        int c = cf * 16 + lr;
        int mrow = w * 16 + rb + rg;
        mt[mrow * 128 + (c ^ ((mrow & 7) << 3))] =
            f2b((e1[cf][rg] - mu) * rs * gM[c] + bM[c]);
      }
    }
  }

  for (int h = 0; h < 2; h++) {
    __syncthreads();
    stageW(w1f + (size_t)h * 32 * 512);
    __syncthreads();
    f32x4 acc[8] = {};
    __builtin_amdgcn_s_setprio(1);
#pragma unroll
    for (int ks = 0; ks < 4; ks++) {
      int kof = ks * 32 + lk8;
      short8 af = *reinterpret_cast<const short8*>(&mt[arow * 128 + (kof ^ swz)]);
#pragma unroll
      for (int cf = 0; cf < 8; cf++) {
        short8 bf = *reinterpret_cast<const short8*>(&Wb[(cf * 4 + ks) * 512 + lane * 8]);
        acc[cf] = __builtin_amdgcn_mfma_f32_16x16x32_bf16(af, bf, acc[cf], 0, 0, 0);
      }
    }
    __builtin_amdgcn_s_setprio(0);
#pragma unroll
    for (int cf = 0; cf < 8; cf++) {
      int c2 = (h * 8 + cf) * 16 + lr;
#pragma unroll
      for (int rg = 0; rg < 4; rg++) {
        int mrow = w * 16 + rb + rg;
        As[mrow * 256 + (c2 ^ ((mrow & 7) << 3))] = f2b(gelu_f(acc[cf][rg] + mb1[c2]));
      }
    }
  }

  for (int h = 0; h < 2; h++) {
    __syncthreads();
    stageW(w2f + (size_t)h * 32 * 512);
    __syncthreads();
    f32x4 acc[4] = {};
    __builtin_amdgcn_s_setprio(1);
#pragma unroll
    for (int ks = 0; ks < 8; ks++) {
      int kof = ks * 32 + lk8;
      short8 af = *reinterpret_cast<const short8*>(&As[arow * 256 + (kof ^ swz)]);
#pragma unroll
      for (int cf = 0; cf < 4; cf++) {
        short8 bf = *reinterpret_cast<const short8*>(&Wb[(cf * 8 + ks) * 512 + lane * 8]);
        acc[cf] = __builtin_amdgcn_mfma_f32_16x16x32_bf16(af, bf, acc[cf], 0, 0, 0);
      }
    }
    __builtin_amdgcn_s_setprio(0);
#pragma unroll
    for (int cf = 0; cf < 4; cf++) {
      int cg = h * 4 + cf;
      int c = cg * 16 + lr;
#pragma unroll
      for (int rg = 0; rg < 4; rg++) {
        int mrow = w * 16 + rb + rg;
        mt[mrow * 128 + (c ^ ((mrow & 7) << 3))] = f2b(e1[cg][rg] + acc[cf][rg] + mb2[c]);
      }
    }
  }

  __syncthreads();
#pragma unroll
  for (int p = 0; p < 4; p++) {
    int u = p * 256 + tid;
    int row = u >> 4, col8 = (u & 15) * 8;
    int gr = r0 + row;
    if (gr < RE_) {
      short8 v = *reinterpret_cast<const short8*>(&mt[row * 128 + (col8 ^ ((row & 7) << 3))]);
      __builtin_nontemporal_store(v, reinterpret_cast<short8*>(&eout[(size_t)gr * 128 + col8]));
    }
  }
}

// ---------------- head ----------------
__global__ void k_head(const float* __restrict__ node, const float* __restrict__ Wo1,
                       const float* __restrict__ bo1, const float* __restrict__ Wo2,
                       const float* __restrict__ bo2, float* __restrict__ out) {
  int b = blockIdx.x;
  int tid = threadIdx.x;  // 128
  __shared__ float gsh[D_];
  __shared__ float h1[D_];
  float s = 0.f;
  for (int n = 0; n < N_; n++) s += node[((size_t)b * N_ + n) * D_ + tid];
  gsh[tid] = s * (1.f / 67.f);
  __syncthreads();
  float a = 0.f;
  for (int k = 0; k < D_; k++) a += gsh[k] * Wo1[k * D_ + tid];
  h1[tid] = fmaxf(a + bo1[tid], 0.f);
  __syncthreads();
  if (tid < DOUT_) {
    float r = 0.f;
    for (int k = 0; k < D_; k++) r += h1[k] * Wo2[k * DOUT_ + tid];
    out[b * DOUT_ + tid] = r + bo2[tid];
  }
}

// ---------------- host ----------------
extern "C" void kernel_launch(void* const* d_in, const int* in_sizes, int n_in,
                              void* d_out, int out_size, void* d_ws, size_t ws_size,
                              hipStream_t stream) {
  const float* w0   = (const float*)d_in[0];
  const float* w1   = (const float*)d_in[1];
  const float* w2   = (const float*)d_in[2];
  const float* b0   = (const float*)d_in[3];
  const float* b1   = (const float*)d_in[4];
  const float* b2   = (const float*)d_in[5];
  const float* pwW  = (const float*)d_in[6];
  const float* pwb  = (const float*)d_in[7];
  const float* pbW  = (const float*)d_in[8];
  const float* pbb  = (const float*)d_in[9];
  const float* niW  = (const float*)d_in[10];
  const float* nib  = (const float*)d_in[11];
  const float* eiW  = (const float*)d_in[12];
  const float* eib  = (const float*)d_in[13];
  const float* pos  = (const float*)d_in[14];
  const float* alng = (const float*)d_in[15];
  const float* alnb = (const float*)d_in[16];
  const float* Wqkvn= (const float*)d_in[17];
  const float* Wqkve= (const float*)d_in[18];
  const float* Wao  = (const float*)d_in[19];
  const float* bao  = (const float*)d_in[20];
  const float* Wl0  = (const float*)d_in[21];
  const float* bl0  = (const float*)d_in[22];
  const float* nlng = (const float*)d_in[23];
  const float* nlnb = (const float*)d_in[24];
  const float* nW1  = (const float*)d_in[25];
  const float* nb1  = (const float*)d_in[26];
  const float* nW2  = (const float*)d_in[27];
  const float* nb2  = (const float*)d_in[28];
  const float* elng = (const float*)d_in[29];
  const float* elnb = (const float*)d_in[30];
  const float* We   = (const float*)d_in[31];
  const float* be   = (const float*)d_in[32];
  const float* Ws   = (const float*)d_in[33];
  const float* bs   = (const float*)d_in[34];
  const float* Wt   = (const float*)d_in[35];
  const float* bt   = (const float*)d_in[36];
  const float* Wer  = (const float*)d_in[37];
  const float* Wec  = (const float*)d_in[38];
  const float* We1  = (const float*)d_in[39];
  const float* be1  = (const float*)d_in[40];
  const float* Wel0 = (const float*)d_in[41];
  const float* bel0 = (const float*)d_in[42];
  const float* mlng = (const float*)d_in[43];
  const float* mlnb = (const float*)d_in[44];
  const float* mW1  = (const float*)d_in[45];
  const float* mb1  = (const float*)d_in[46];
  const float* mW2  = (const float*)d_in[47];
  const float* mb2  = (const float*)d_in[48];
  const float* Wo1  = (const float*)d_in[49];
  const float* bo1  = (const float*)d_in[50];
  const float* Wo2  = (const float*)d_in[51];
  const float* bo2  = (const float*)d_in[52];
  float* outp = (float*)d_out;

  const size_t E = (size_t)RE_ * D_;
  const size_t NODE = (size_t)RN_ * D_;
  const int DD = D_ * D_;

  float* ws = (float*)d_ws;
  size_t off = 0;
  auto alloc = [&](size_t nf) { float* p = ws + off; off += nf; return p; };
  ushort* edgeA = (ushort*)alloc(E / 2);
  ushort* edgeB = (ushort*)alloc(E / 2);
  float* stats = alloc(2 * (size_t)RE_);
  float* node  = alloc(NODE);
  float* qkvn  = alloc(3 * NODE);
  float* obuf  = alloc(NODE);
  float* rmean = alloc(NODE);
  float* cmean = alloc(NODE);
  float* rvec  = alloc(NODE);
  float* cvec  = alloc(NODE);
  float* WcN   = alloc((size_t)L_ * DD);
  float* bcN   = alloc((size_t)L_ * D_);
  float* WcE   = alloc((size_t)L_ * DD);
  float* bcE   = alloc((size_t)L_ * D_);
  float* vecs  = alloc(4 * D_);
  ushort* wbf   = (ushort*)alloc(245760);
  ushort* wq_fm = wbf;
  ushort* we_fm = wq_fm + (size_t)L_ * 49152;
  ushort* wce_fm= we_fm + (size_t)L_ * 32768;
  ushort* w1_fm = wce_fm + (size_t)L_ * 16384;
  ushort* w2_fm = w1_fm + (size_t)L_ * 32768;
  (void)ws_size; (void)in_sizes; (void)n_in; (void)out_size;

  k_comb<<<(2 * L_ * DD + 255) / 256, 256, 0, stream>>>(Wao, bao, Wl0, bl0, We1, be1, Wel0, bel0,
                                                        WcN, bcN, WcE, bcE);
  k_prepw<<<1920, 256, 0, stream>>>(Wqkve, We, WcE, mW1, mW2, wq_fm, we_fm, wce_fm, w1_fm, w2_fm);
  k_vecs<<<1, 128, 0, stream>>>(pbW, pbb, niW, nib, pwW, pwb, eiW, eib, vecs);
  k_init_node<<<(RN_ * D_ + 255) / 256, 256, 0, stream>>>(b0, b1, b2, vecs, pos, node);
  k_init_edge<<<(int)((E + 255) / 256), 256, 0, stream>>>(w0, w1, w2, vecs, edgeA);

  const int GE = (RE_ + 63) / 64;  // 2245
  const int GN = (RN_ + 63) / 64;  // 34
  const int GM = RN_ / 16;         // 134

  for (int l = 0; l < L_; l++) {
    ushort* ein  = (l & 1) ? edgeB : edgeA;
    ushort* eout = (l & 1) ? edgeA : edgeB;
    const float* Wqn = Wqkvn + (size_t)l * D_ * 384;

    k_lnqkv<<<dim3(GN, 6), 256, 0, stream>>>(node, alng + l * D_, alnb + l * D_, Wqn, qkvn);
    k_eattn<<<RN_, 256, 0, stream>>>(ein, qkvn, wq_fm + (size_t)l * 49152,
                                     elng + l * D_, elnb + l * D_, stats, rmean, obuf);
    k_nodemlp<<<GM, 256, 0, stream>>>(node, obuf, WcN + (size_t)l * DD, bcN + l * D_,
                                      nlng + l * D_, nlnb + l * D_,
                                      nW1 + (size_t)l * D_ * 256, nb1 + l * 256,
                                      nW2 + (size_t)l * 256 * D_, nb2 + l * D_);

    k_colmean<<<RN_, 128, 0, stream>>>(ein, stats, elng + l * D_, elnb + l * D_, cmean);
    k_nvec<<<dim3(GN, 2, 2), 256, 0, stream>>>(node, rmean, cmean,
                                               Ws + (size_t)l * DD, Wer + (size_t)l * DD,
                                               Wt + (size_t)l * DD, Wec + (size_t)l * DD,
                                               bs + l * D_, be + l * D_, bt + l * D_,
                                               rvec, cvec);

    k_fedge<<<GE, 256, 0, stream>>>(ein, eout, stats,
                                    elng + l * D_, elnb + l * D_,
                                    we_fm + (size_t)l * 32768, rvec, cvec,
                                    wce_fm + (size_t)l * 16384, bcE + l * D_,
                                    mlng + l * D_, mlnb + l * D_,
                                    w1_fm + (size_t)l * 32768, mb1 + l * 256,
                                    w2_fm + (size_t)l * 32768, mb2 + l * D_);
  }

  k_head<<<B_, 128, 0, stream>>>(node, Wo1, bo1, Wo2, bo2, outp);
}

// Round 15
// 1003.675 us; speedup vs baseline: 1.2994x; 1.1609x over previous
//
#include <hip/hip_runtime.h>
#include <math.h>

constexpr int B_ = 32, N_ = 67, D_ = 128, H_ = 8, DH_ = 16, L_ = 3;
constexpr int NN_ = N_ * N_;          // 4489
constexpr int RN_ = B_ * N_;          // 2144
constexpr int RE_ = B_ * NN_;         // 143648
constexpr int DOUT_ = 10;

typedef __attribute__((ext_vector_type(8))) short short8;
typedef __attribute__((ext_vector_type(4))) float f32x4;

// branchless tanh-approx GELU (max abs err ~3e-4; downstream-amplified ~1e-4 << 1.5e-3 tol)
__device__ __forceinline__ float gelu_f(float x) {
  float u = x * (0.7978845608028654f + 0.035677408136f * x * x);
  float e = __expf(-2.f * u);
  return x * (1.f / (1.f + e));   // 0.5x(1+tanh(u)) == x*sigmoid(2u)
}
__device__ __forceinline__ ushort f2b(float x) {
  union { float f; unsigned u; } v; v.f = x;
  return (ushort)((v.u + 0x7FFFu + ((v.u >> 16) & 1u)) >> 16);
}
__device__ __forceinline__ float b2f(ushort u) {
  union { unsigned u; float f; } v; v.u = (unsigned)u << 16; return v.f;
}

// ---------------- precompute: combined weights (Wao@Wl0, We1@Wel0) ----------------
__global__ void k_comb(const float* __restrict__ Wao, const float* __restrict__ bao,
                       const float* __restrict__ Wl0, const float* __restrict__ bl0,
                       const float* __restrict__ We1, const float* __restrict__ be1,
                       const float* __restrict__ Wel0, const float* __restrict__ bel0,
                       float* WcN, float* bcN, float* WcE, float* bcE) {
  int t = blockIdx.x * blockDim.x + threadIdx.x;
  const int half = L_ * D_ * D_;
  if (t >= 2 * half) return;
  int which = t / half;
  int u = t - which * half;
  int l = u / (D_ * D_);
  int ij = u - l * (D_ * D_);
  int i = ij >> 7, j = ij & 127;
  const float* A  = (which == 0 ? Wao : We1) + (size_t)l * D_ * D_;
  const float* Bm = (which == 0 ? Wl0 : Wel0) + (size_t)l * D_ * D_;
  float s = 0.f;
  for (int k = 0; k < D_; k++) s += A[i * D_ + k] * Bm[k * D_ + j];
  if (which == 0) WcN[u] = s; else WcE[u] = s;
  if (i == 0) {
    const float* ba = (which == 0 ? bao : be1) + l * D_;
    const float* bl = (which == 0 ? bl0 : bel0) + l * D_;
    float sb = 0.f;
    for (int k = 0; k < D_; k++) sb += ba[k] * Bm[k * D_ + j];
    if (which == 0) bcN[l * D_ + j] = sb + bl[j]; else bcE[l * D_ + j] = sb + bl[j];
  }
}

// ---------------- precompute: fragment-major bf16 weights ----------------
__device__ __forceinline__ float enc_src(const float* src, int K, int C, int NKS, int r, int l) {
  int frag = r >> 9;
  int within = r & 511;
  int lane = within >> 3, j = within & 7;
  int cf = frag / NKS, ks = frag - cf * NKS;
  int k = ks * 32 + (lane >> 4) * 8 + j;
  int c = cf * 16 + (lane & 15);
  return src[(size_t)l * K * C + (size_t)k * C + c];
}

__global__ void k_prepw(const float* __restrict__ Wqkve, const float* __restrict__ We,
                        const float* __restrict__ WcE, const float* __restrict__ mW1,
                        const float* __restrict__ mW2,
                        ushort* wq, ushort* we, ushort* wce, ushort* w1, ushort* w2) {
  int t = blockIdx.x * 256 + threadIdx.x;
  const int S0 = L_ * 49152, S1 = L_ * 32768, S2 = L_ * 16384, S3 = L_ * 32768, S4 = L_ * 32768;
  if (t < S0) { int l = t / 49152, r = t % 49152; wq[t]  = f2b(enc_src(Wqkve, 128, 384, 4, r, l)); return; }
  t -= S0;
  if (t < S1) { int l = t / 32768, r = t % 32768; we[t]  = f2b(enc_src(We,   256, 128, 8, r, l)); return; }
  t -= S1;
  if (t < S2) { int l = t / 16384, r = t % 16384; wce[t] = f2b(enc_src(WcE,  128, 128, 4, r, l)); return; }
  t -= S2;
  if (t < S3) { int l = t / 32768, r = t % 32768; w1[t]  = f2b(enc_src(mW1,  128, 256, 4, r, l)); return; }
  t -= S3;
  if (t < S4) { int l = t / 32768, r = t % 32768; w2[t]  = f2b(enc_src(mW2,  256, 128, 8, r, l)); return; }
}

// ---------------- precompute: folded input-embed vectors ----------------
__global__ void k_vecs(const float* pbW, const float* pbb, const float* niW, const float* nib,
                       const float* pwW, const float* pwb, const float* eiW, const float* eib,
                       float* vecs) {
  int j = threadIdx.x;
  if (j >= D_) return;
  float u = 0, c = 0, v = 0, ce = 0;
  for (int k = 0; k < D_; k++) {
    u  += pbW[k] * niW[k * D_ + j];
    c  += pbb[k] * niW[k * D_ + j];
    v  += pwW[k] * eiW[k * D_ + j];
    ce += pwb[k] * eiW[k * D_ + j];
  }
  vecs[j] = u; vecs[D_ + j] = c + nib[j]; vecs[2 * D_ + j] = v; vecs[3 * D_ + j] = ce + eib[j];
}

// ---------------- init node / edge ----------------
__global__ void k_init_node(const float* __restrict__ b0, const float* __restrict__ b1,
                            const float* __restrict__ b2, const float* __restrict__ vecs,
                            const float* __restrict__ pos, float* __restrict__ node) {
  int idx = blockIdx.x * blockDim.x + threadIdx.x;
  if (idx >= RN_ * D_) return;
  int r = idx >> 7, d = idx & 127;
  int b = r / N_, n = r - b * N_;
  float nf = 0.f;
  if (n >= 2 && n < 34)       nf = b0[b * 32 + n - 2];
  else if (n >= 34 && n < 66) nf = b1[b * 32 + n - 34];
  else if (n == 66)           nf = b2[b];
  int pr = (n == 0) ? 0 : (n == 1) ? 1 : (n < 34) ? 2 : (n < 66) ? 3 : 4;
  node[idx] = nf * vecs[d] + vecs[D_ + d] + pos[pr * D_ + d];
}

__global__ void k_init_edge(const float* __restrict__ w0, const float* __restrict__ w1,
                            const float* __restrict__ w2, const float* __restrict__ vecs,
                            ushort* __restrict__ edge) {
  int idx = blockIdx.x * blockDim.x + threadIdx.x;
  if (idx >= RE_ * D_) return;
  int r = idx >> 7, d = idx & 127;
  int b = r / NN_;
  int rem = r - b * NN_;
  int n = rem / N_, m = rem - n * N_;
  float ef = 0.f;
  if (n < 2)        { if (m >= 2 && m < 34)  ef = w0[(b * 2 + n) * 32 + (m - 2)]; }
  else if (n < 34)  { if (m >= 34 && m < 66) ef = w1[(b * 32 + (n - 2)) * 32 + (m - 34)]; }
  else if (n < 66)  { if (m == 66)           ef = w2[b * 32 + (n - 34)]; }
  edge[idx] = f2b(ef * vecs[2 * D_ + d] + vecs[3 * D_ + d]);
}

// ---------------- fused node LN + QKV projection (no bias) ----------------
__global__ __launch_bounds__(256) void k_lnqkv(
    const float* __restrict__ node, const float* __restrict__ g, const float* __restrict__ bb,
    const float* __restrict__ W, float* __restrict__ out) {
  __shared__ float As[16][68];
  __shared__ float Wsh[16][68];
  __shared__ float stmu[64], strs[64];
  int r0 = blockIdx.x * 64, c0 = blockIdx.y * 64;
  int tid = threadIdx.x;
  // per-row LN stats (4 threads / row)
  {
    int row = tid >> 2, part = tid & 3;
    int gr = r0 + row;
    int grc = (gr < RN_) ? gr : 0;
    const float* x = node + (size_t)grc * 128 + part * 32;
    float s = 0.f, q = 0.f;
#pragma unroll
    for (int i = 0; i < 8; i++) {
      float4 v = *reinterpret_cast<const float4*>(&x[i * 4]);
      s += v.x + v.y + v.z + v.w;
      q += v.x * v.x + v.y * v.y + v.z * v.z + v.w * v.w;
    }
    for (int o = 1; o < 4; o <<= 1) { s += __shfl_xor(s, o); q += __shfl_xor(q, o); }
    if (part == 0) {
      float mu = s * (1.f / 128.f);
      stmu[row] = mu;
      strs[row] = rsqrtf(q * (1.f / 128.f) - mu * mu + 1e-5f);
    }
  }
  __syncthreads();
  int tr = tid >> 4, tc = tid & 15;
  float acc[4][4] = {};
  for (int kk = 0; kk < 128; kk += 16) {
#pragma unroll
    for (int i = 0; i < 4; i++) {
      int lin = tid + i * 256;
      int r_in = lin >> 4, k_in = lin & 15;
      int r = r0 + r_in;
      float v = 0.f;
      if (r < RN_) {
        int k = kk + k_in;
        v = (node[(size_t)r * 128 + k] - stmu[r_in]) * strs[r_in] * g[k] + bb[k];
      }
      As[k_in][r_in] = v;
    }
#pragma unroll
    for (int i = 0; i < 4; i++) {
      int lin = tid + i * 256;
      int k_in = lin >> 6, c_in = lin & 63;
      Wsh[k_in][c_in] = W[(size_t)(kk + k_in) * 384 + c0 + c_in];
    }
    __syncthreads();
#pragma unroll
    for (int k = 0; k < 16; k++) {
      float4 a4 = *reinterpret_cast<const float4*>(&As[k][tr * 4]);
      float4 b4 = *reinterpret_cast<const float4*>(&Wsh[k][tc * 4]);
      float av[4] = {a4.x, a4.y, a4.z, a4.w};
      float bv[4] = {b4.x, b4.y, b4.z, b4.w};
#pragma unroll
      for (int i = 0; i < 4; i++)
#pragma unroll
        for (int j = 0; j < 4; j++) acc[i][j] += av[i] * bv[j];
    }
    __syncthreads();
  }
#pragma unroll
  for (int i = 0; i < 4; i++) {
    int r = r0 + tr * 4 + i;
    if (r >= RN_) continue;
#pragma unroll
    for (int j = 0; j < 4; j++) {
      int c = c0 + tc * 4 + j;
      out[(size_t)r * 384 + c] = acc[i][j];
    }
  }
}

// ---------------- fused node residual + MLP ----------------
__global__ __launch_bounds__(256) void k_nodemlp(
    float* __restrict__ node, const float* __restrict__ obuf,
    const float* __restrict__ WcN, const float* __restrict__ bcN,
    const float* __restrict__ g, const float* __restrict__ bb,
    const float* __restrict__ nW1, const float* __restrict__ nb1,
    const float* __restrict__ nW2, const float* __restrict__ nb2) {
  __shared__ float As[16][17];
  __shared__ float Wsh[16][132];
  __shared__ ushort Hs[16][136];
  __shared__ ushort Ts[16][264];
  int r0 = blockIdx.x * 16;
  int tid = threadIdx.x;
  int tr = tid >> 4, tc = tid & 15;     // row tr, 8-col group tc
  size_t grow = (size_t)(r0 + tr) * 128;

  auto stageW = [&](const float* src, int ld, int kk, int cbase) {
    int k = tid & 15, cp = tid >> 4;
    const float* s = &src[(size_t)(kk + k) * ld + cbase + cp * 8];
    float* d = &Wsh[k][cp * 8];
#pragma unroll
    for (int j = 0; j < 8; j++) d[j] = s[j];
  };

  // phase 1: acc = obuf @ WcN (K=128)
  float acc[8] = {};
  for (int kk = 0; kk < 128; kk += 16) {
    As[tr][tc] = obuf[grow + kk + tc];
    stageW(WcN, 128, kk, 0);
    __syncthreads();
#pragma unroll
    for (int k = 0; k < 16; k++) {
      float a = As[tr][k];
#pragma unroll
      for (int j = 0; j < 8; j++) acc[j] += a * Wsh[k][tc * 8 + j];
    }
    __syncthreads();
  }
  // phase 2: nd = node + acc + bcN ; LN -> Hs (bf16)
  float nd[8];
  float s = 0.f, q = 0.f;
#pragma unroll
  for (int j = 0; j < 8; j++) {
    int c = tc * 8 + j;
    float v = node[grow + c] + acc[j] + bcN[c];
    nd[j] = v; s += v; q += v * v;
  }
  for (int o = 1; o < 16; o <<= 1) { s += __shfl_xor(s, o); q += __shfl_xor(q, o); }
  float mu = s * (1.f / 128.f);
  float rs = rsqrtf(q * (1.f / 128.f) - mu * mu + 1e-5f);
#pragma unroll
  for (int j = 0; j < 8; j++) {
    int c = tc * 8 + j;
    Hs[tr][c] = f2b((nd[j] - mu) * rs * g[c] + bb[c]);
  }
  // phase 3: Ts = gelu(Hs @ nW1 + nb1), C=256 in 2 halves of 128
  for (int ch = 0; ch < 2; ch++) {
    float a2[8] = {};
    for (int kk = 0; kk < 128; kk += 16) {
      __syncthreads();
      stageW(nW1, 256, kk, ch * 128);
      __syncthreads();
#pragma unroll
      for (int k = 0; k < 16; k++) {
        float a = b2f(Hs[tr][kk + k]);
#pragma unroll
        for (int j = 0; j < 8; j++) a2[j] += a * Wsh[k][tc * 8 + j];
      }
    }
#pragma unroll
    for (int j = 0; j < 8; j++) {
      int c = ch * 128 + tc * 8 + j;
      Ts[tr][c] = f2b(gelu_f(a2[j] + nb1[c]));
    }
  }
  // phase 4: node = nd + Ts @ nW2 + nb2 (K=256)
  float a3[8] = {};
  for (int kk = 0; kk < 256; kk += 16) {
    __syncthreads();
    stageW(nW2, 128, kk, 0);
    __syncthreads();
#pragma unroll
    for (int k = 0; k < 16; k++) {
      float a = b2f(Ts[tr][kk + k]);
#pragma unroll
      for (int j = 0; j < 8; j++) a3[j] += a * Wsh[k][tc * 8 + j];
    }
  }
#pragma unroll
  for (int j = 0; j < 8; j++) {
    int c = tc * 8 + j;
    node[grow + c] = nd[j] + a3[j] + nb2[c];
  }
}

// ---------------- fused rvec/cvec: out = node@W1 + A2@W2 + bias ----------------
__global__ __launch_bounds__(256) void k_nvec(
    const float* __restrict__ node, const float* __restrict__ rmean, const float* __restrict__ cmean,
    const float* __restrict__ Ws, const float* __restrict__ Wer,
    const float* __restrict__ Wt, const float* __restrict__ Wec,
    const float* __restrict__ bs, const float* __restrict__ be, const float* __restrict__ bt,
    float* __restrict__ rvec, float* __restrict__ cvec) {
  __shared__ float Ash[16][68];
  __shared__ float Wsh[16][68];
  int which = blockIdx.z;
  const float* A2 = which ? cmean : rmean;
  const float* W1 = which ? Wt : Ws;
  const float* W2 = which ? Wec : Wer;
  float* out = which ? cvec : rvec;
  int r0 = blockIdx.x * 64, c0 = blockIdx.y * 64;
  int tid = threadIdx.x, tr = tid >> 4, tc = tid & 15;
  float acc[4][4] = {};
  for (int kk = 0; kk < 256; kk += 16) {
#pragma unroll
    for (int i = 0; i < 4; i++) {
      int lin = tid + i * 256;
      int r_in = lin >> 4, k_in = lin & 15;
      int r = r0 + r_in, k = kk + k_in;
      float v = 0.f;
      if (r < RN_) v = (k < 128) ? node[(size_t)r * 128 + k] : A2[(size_t)r * 128 + (k - 128)];
      Ash[k_in][r_in] = v;
    }
#pragma unroll
    for (int i = 0; i < 4; i++) {
      int lin = tid + i * 256;
      int k_in = lin >> 6, c_in = lin & 63;
      int k = kk + k_in, c = c0 + c_in;
      Wsh[k_in][c_in] = (k < 128) ? W1[(size_t)k * 128 + c] : W2[(size_t)(k - 128) * 128 + c];
    }
    __syncthreads();
#pragma unroll
    for (int k = 0; k < 16; k++) {
      float4 a4 = *reinterpret_cast<const float4*>(&Ash[k][tr * 4]);
      float4 b4 = *reinterpret_cast<const float4*>(&Wsh[k][tc * 4]);
      float av[4] = {a4.x, a4.y, a4.z, a4.w};
      float bv[4] = {b4.x, b4.y, b4.z, b4.w};
#pragma unroll
      for (int i = 0; i < 4; i++)
#pragma unroll
        for (int j = 0; j < 4; j++) acc[i][j] += av[i] * bv[j];
    }
    __syncthreads();
  }
#pragma unroll
  for (int i = 0; i < 4; i++) {
    int r = r0 + tr * 4 + i;
    if (r >= RN_) continue;
#pragma unroll
    for (int j = 0; j < 4; j++) {
      int c = c0 + tc * 4 + j;
      float bias = which ? bt[c] : (bs[c] + be[c]);
      out[(size_t)r * 128 + c] = acc[i][j] + bias;
    }
  }
}

// ---------------- fused per-(b,n) attention + edge LN stats + rowmean ----------------
__global__ __launch_bounds__(256, 3) void k_eattn(
    const ushort* __restrict__ edge, const float* __restrict__ qkvn,
    const ushort* __restrict__ wqf,   // fragment-major [24cf][4ks][64][8]
    const float* __restrict__ gE, const float* __restrict__ bE,
    float* __restrict__ stats, float* __restrict__ rmean,
    float* __restrict__ obuf) {
  __shared__ __align__(16) ushort ed[68 * 128];   // 17.4 KB
  __shared__ __align__(16) ushort Eb[68 * 202];   // 27.5 KB
  __shared__ float qn_s[384];
  __shared__ float sc[4][68];
  __shared__ float red[4][16][4];
  __shared__ float stmu[68], strs[68];
  int bn = blockIdx.x;
  int b = bn / N_;
  int tid = threadIdx.x;
  int w = tid >> 6, lane = tid & 63, lr = lane & 15, lk8 = (lane >> 4) * 8;
  int swz = (lr & 7) << 3;
  int rb = (lane >> 4) * 4;
  size_t ebase = (size_t)bn * N_ * 128;

  // stage bf16 edge tile (NT: single-use stream here) + per-row LN stats
  for (int i = 0; i < 5; i++) {
    int u = tid + i * 256;
    if (u < 67 * 16) {
      int row = u >> 4, k8 = (u & 15) * 8;
      short8 t = __builtin_nontemporal_load(
          reinterpret_cast<const short8*>(&edge[ebase + (size_t)row * 128 + k8]));
      *reinterpret_cast<short8*>(&ed[row * 128 + (k8 ^ ((row & 7) << 3))]) = t;
      float s = 0.f, q = 0.f;
#pragma unroll
      for (int j = 0; j < 8; j++) { float v = b2f((ushort)t[j]); s += v; q += v * v; }
      for (int o = 8; o; o >>= 1) { s += __shfl_xor(s, o); q += __shfl_xor(q, o); }
      if ((u & 15) == 0) {
        float mu = s * (1.f / 128.f);
        float rs = rsqrtf(q * (1.f / 128.f) - mu * mu + 1e-5f);
        stmu[row] = mu; strs[row] = rs;
        stats[2 * (size_t)(bn * N_ + row)] = mu;
        stats[2 * (size_t)(bn * N_ + row) + 1] = rs;
      }
    }
  }
  for (int i = tid; i < 384; i += 256) qn_s[i] = qkvn[(size_t)bn * 384 + i];
  __syncthreads();
  // rowmean of LN(edge)
  if (tid < 128) {
    float s = 0.f;
    for (int m = 0; m < 67; m++)
      s += (b2f(ed[m * 128 + (tid ^ ((m & 7) << 3))]) - stmu[m]) * strs[m];
    rmean[(size_t)bn * 128 + tid] = gE[tid] * (s * (1.f / 67.f)) + bE[tid];
  }

  // 2 chunks of 192 cols (4 heads each); wave w = head (ch*4 + w)
  for (int ch = 0; ch < 2; ch++) {
    int h0 = ch * 4;
    f32x4 acc[5][3] = {};
    __builtin_amdgcn_s_setprio(1);
#pragma unroll
    for (int ks = 0; ks < 4; ks++) {
      int kof = ks * 32 + lk8;
      short8 af[5];
#pragma unroll
      for (int rf = 0; rf < 5; rf++)
        af[rf] = *reinterpret_cast<const short8*>(&ed[(rf * 16 + lr) * 128 + (kof ^ swz)]);
#pragma unroll
      for (int cl = 0; cl < 3; cl++) {
        short8 bf = *reinterpret_cast<const short8*>(
            &wqf[(size_t)(((ch * 12 + w * 3 + cl) * 4 + ks) * 64 + lane) * 8]);
#pragma unroll
        for (int rf = 0; rf < 5; rf++)
          acc[rf][cl] = __builtin_amdgcn_mfma_f32_16x16x32_bf16(af[rf], bf, acc[rf][cl], 0, 0, 0);
      }
    }
    __builtin_amdgcn_s_setprio(0);
#pragma unroll
    for (int rf = 0; rf < 5; rf++)
#pragma unroll
      for (int cl = 0; cl < 3; cl++) {
        int colc = (w * 3 + cl) * 16 + lr;
#pragma unroll
        for (int rg = 0; rg < 4; rg++) {
          int er = rf * 16 + rb + rg;
          if (er < 67) Eb[er * 202 + colc] = f2b(acc[rf][cl][rg]);
        }
      }
    __syncthreads();
    // scores (4 heads x 67)
    for (int idx = tid; idx < 268; idx += 256) {
      int h2 = idx / 67, m = idx - h2 * 67;
      const ushort* e = &Eb[m * 202 + h2 * 48];
      const float* kn = &qkvn[(size_t)(b * N_ + m) * 384 + (h0 + h2) * 48 + 16];
      const float* qn = &qn_s[(h0 + h2) * 48];
      float s2 = 0.f;
#pragma unroll
      for (int d = 0; d < 16; d++)
        s2 += (qn[d] + b2f(e[d])) * (kn[d] + b2f(e[16 + d]));
      sc[h2][m] = s2 * 0.25f;
    }
    __syncthreads();
    // softmax: wave w -> head w of chunk
    {
      float v0 = (lane < 67) ? sc[w][lane] : -1e30f;
      float v1 = (lane < 3) ? sc[w][lane + 64] : -1e30f;
      float mx = fmaxf(v0, v1);
      for (int o = 32; o; o >>= 1) mx = fmaxf(mx, __shfl_xor(mx, o));
      float e0 = (lane < 67) ? __expf(v0 - mx) : 0.f;
      float e1 = (lane < 3) ? __expf(v1 - mx) : 0.f;
      float ss = e0 + e1;
      for (int o = 32; o; o >>= 1) ss += __shfl_xor(ss, o);
      float inv = 1.f / ss;
      if (lane < 67) sc[w][lane] = e0 * inv;
      if (lane < 3) sc[w][lane + 64] = e1 * inv;
    }
    __syncthreads();
    // PV
    {
      int item = tid >> 2, c = tid & 3;
      int h2 = item >> 4, d = item & 15;
      float p = 0.f;
      for (int m = c; m < 67; m += 4) {
        float v = qkvn[(size_t)(b * N_ + m) * 384 + (h0 + h2) * 48 + 32 + d]
                + b2f(Eb[m * 202 + h2 * 48 + 32 + d]);
        p += sc[h2][m] * v;
      }
      red[h2][d][c] = p;
    }
    __syncthreads();
    if (tid < 64) {
      int h2 = tid >> 4, d = tid & 15;
      obuf[(size_t)bn * 128 + (h0 + h2) * 16 + d] =
          red[h2][d][0] + red[h2][d][1] + red[h2][d][2] + red[h2][d][3];
    }
    __syncthreads();
  }
}

// ---------------- col means of LN(edge) ----------------
__global__ void k_colmean(const ushort* __restrict__ edge, const float* __restrict__ stats,
                          const float* __restrict__ g, const float* __restrict__ bb,
                          float* __restrict__ cmean) {
  int bm = blockIdx.x;
  int b = bm / N_, m = bm - b * N_;
  int d = threadIdx.x;
  float s = 0.f;
  for (int n = 0; n < N_; n++) {
    size_t r = (size_t)b * NN_ + (size_t)n * N_ + m;
    s += (b2f(edge[r * D_ + d]) - stats[2 * r]) * stats[2 * r + 1];
  }
  cmean[(size_t)bm * D_ + d] = g[d] * (s * (1.f / 67.f)) + bb[d];
}

// ---------------- fully-fused edge block: LDS-staged frag-major weights ----------------
__global__ __launch_bounds__(256, 2) void k_fedge(
    const ushort* __restrict__ ein, ushort* __restrict__ eout,
    const float* __restrict__ stats,
    const float* __restrict__ gE, const float* __restrict__ bE,
    const ushort* __restrict__ wef,
    const float* __restrict__ rvec, const float* __restrict__ cvec,
    const ushort* __restrict__ wcef,
    const float* __restrict__ bcE,
    const float* __restrict__ gM, const float* __restrict__ bM,
    const ushort* __restrict__ w1f,
    const float* __restrict__ mb1,
    const ushort* __restrict__ w2f,
    const float* __restrict__ mb2) {
  __shared__ __align__(16) ushort As[64 * 256];
  __shared__ __align__(16) ushort mt[64 * 128];
  __shared__ __align__(16) ushort Wb[32 * 512];
  int tid = threadIdx.x;
  int r0 = blockIdx.x * 64;
  int w = tid >> 6, lane = tid & 63, lr = lane & 15, lk8 = (lane >> 4) * 8;
  int swz = (lr & 7) << 3;
  int rb = (lane >> 4) * 4;
  int arow = w * 16 + lr;

  auto stageW = [&](const ushort* src) {
#pragma unroll
    for (int i = 0; i < 8; i++) {
      int u = tid + i * 256;
      short8 t = *reinterpret_cast<const short8*>(&src[(size_t)u * 8]);
      *reinterpret_cast<short8*>(&Wb[u * 8]) = t;
    }
  };

#pragma unroll
  for (int i = 0; i < 8; i++) {
    int u = tid + i * 256;
    int row = u >> 5, c8 = (u & 31) * 8;
    int gr = r0 + row;
    int grc = (gr < RE_) ? gr : 0;
    int cc = c8 & 127;
    short8 t;
    float mu, rs;
    if (c8 < 128) {
      size_t srow = (size_t)grc;
      mu = stats[2 * srow]; rs = stats[2 * srow + 1];
      t = *reinterpret_cast<const short8*>(&ein[srow * 128 + cc]);
    } else {
      int b = grc / NN_; int rem = grc - b * NN_;
      int n = rem / N_, m = rem - n * N_;
      size_t srow = (size_t)b * NN_ + (size_t)m * N_ + n;
      mu = stats[2 * srow]; rs = stats[2 * srow + 1];
      t = __builtin_nontemporal_load(reinterpret_cast<const short8*>(&ein[srow * 128 + cc]));
    }
    short8 r8;
#pragma unroll
    for (int j = 0; j < 8; j++) {
      float v = (b2f((ushort)t[j]) - mu) * rs * gE[cc + j] + bE[cc + j];
      r8[j] = (short)f2b(v);
    }
    *reinterpret_cast<short8*>(&As[row * 256 + (c8 ^ ((row & 7) << 3))]) = r8;
  }
  int rvb[4], cvb[4], grows[4]; bool vr[4];
#pragma unroll
  for (int rg = 0; rg < 4; rg++) {
    int gr = r0 + w * 16 + rb + rg;
    vr[rg] = gr < RE_;
    int grc = vr[rg] ? gr : 0;
    grows[rg] = grc;
    int b = grc / NN_; int rem = grc - b * NN_;
    int n = rem / N_, m = rem - n * N_;
    rvb[rg] = (b * N_ + n) * 128;
    cvb[rg] = (b * N_ + m) * 128;
  }
  __syncthreads();

  for (int h = 0; h < 2; h++) {
    if (h) __syncthreads();
    stageW(wef + (size_t)h * 32 * 512);
    __syncthreads();
    f32x4 acc[4] = {};
    __builtin_amdgcn_s_setprio(1);
#pragma unroll
    for (int ks = 0; ks < 8; ks++) {
      int kof = ks * 32 + lk8;
      short8 af = *reinterpret_cast<const short8*>(&As[arow * 256 + (kof ^ swz)]);
#pragma unroll
      for (int cf = 0; cf < 4; cf++) {
        short8 bf = *reinterpret_cast<const short8*>(&Wb[(cf * 8 + ks) * 512 + lane * 8]);
        acc[cf] = __builtin_amdgcn_mfma_f32_16x16x32_bf16(af, bf, acc[cf], 0, 0, 0);
      }
    }
    __builtin_amdgcn_s_setprio(0);
#pragma unroll
    for (int cf = 0; cf < 4; cf++) {
      int c = (h * 4 + cf) * 16 + lr;
#pragma unroll
      for (int rg = 0; rg < 4; rg++) {
        float v = acc[cf][rg] + rvec[rvb[rg] + c] + cvec[cvb[rg] + c];
        int mrow = w * 16 + rb + rg;
        mt[mrow * 128 + (c ^ ((mrow & 7) << 3))] = f2b(gelu_f(v));
      }
    }
  }

  __syncthreads();
  stageW(wcef);
  __syncthreads();
  f32x4 e1[8] = {};
  __builtin_amdgcn_s_setprio(1);
#pragma unroll
  for (int ks = 0; ks < 4; ks++) {
    int kof = ks * 32 + lk8;
    short8 af = *reinterpret_cast<const short8*>(&mt[arow * 128 + (kof ^ swz)]);
#pragma unroll
    for (int cf = 0; cf < 8; cf++) {
      short8 bf = *reinterpret_cast<const short8*>(&Wb[(cf * 4 + ks) * 512 + lane * 8]);
      e1[cf] = __builtin_amdgcn_mfma_f32_16x16x32_bf16(af, bf, e1[cf], 0, 0, 0);
    }
  }
  __builtin_amdgcn_s_setprio(0);
  {
    float sr[4] = {0, 0, 0, 0}, qr[4] = {0, 0, 0, 0};
#pragma unroll
    for (int cf = 0; cf < 8; cf++) {
      int c = cf * 16 + lr;
#pragma unroll
      for (int rg = 0; rg < 4; rg++) {
        float v = e1[cf][rg] + bcE[c] + b2f(ein[(size_t)grows[rg] * 128 + c]);
        e1[cf][rg] = v;
        sr[rg] += v; qr[rg] += v * v;
      }
    }
#pragma unroll
    for (int rg = 0; rg < 4; rg++) {
      float s = sr[rg], q = qr[rg];
      for (int o = 8; o; o >>= 1) { s += __shfl_xor(s, o); q += __shfl_xor(q, o); }
      float mu = s * (1.f / 128.f);
      float rs = rsqrtf(q * (1.f / 128.f) - mu * mu + 1e-5f);
#pragma unroll
      for (int cf = 0; cf < 8; cf++) {
        int c = cf * 16 + lr;
        int mrow = w * 16 + rb + rg;
        mt[mrow * 128 + (c ^ ((mrow & 7) << 3))] =
            f2b((e1[cf][rg] - mu) * rs * gM[c] + bM[c]);
      }
    }
  }

  for (int h = 0; h < 2; h++) {
    __syncthreads();
    stageW(w1f + (size_t)h * 32 * 512);
    __syncthreads();
    f32x4 acc[8] = {};
    __builtin_amdgcn_s_setprio(1);
#pragma unroll
    for (int ks = 0; ks < 4; ks++) {
      int kof = ks * 32 + lk8;
      short8 af = *reinterpret_cast<const short8*>(&mt[arow * 128 + (kof ^ swz)]);
#pragma unroll
      for (int cf = 0; cf < 8; cf++) {
        short8 bf = *reinterpret_cast<const short8*>(&Wb[(cf * 4 + ks) * 512 + lane * 8]);
        acc[cf] = __builtin_amdgcn_mfma_f32_16x16x32_bf16(af, bf, acc[cf], 0, 0, 0);
      }
    }
    __builtin_amdgcn_s_setprio(0);
#pragma unroll
    for (int cf = 0; cf < 8; cf++) {
      int c2 = (h * 8 + cf) * 16 + lr;
#pragma unroll
      for (int rg = 0; rg < 4; rg++) {
        int mrow = w * 16 + rb + rg;
        As[mrow * 256 + (c2 ^ ((mrow & 7) << 3))] = f2b(gelu_f(acc[cf][rg] + mb1[c2]));
      }
    }
  }

  for (int h = 0; h < 2; h++) {
    __syncthreads();
    stageW(w2f + (size_t)h * 32 * 512);
    __syncthreads();
    f32x4 acc[4] = {};
    __builtin_amdgcn_s_setprio(1);
#pragma unroll
    for (int ks = 0; ks < 8; ks++) {
      int kof = ks * 32 + lk8;
      short8 af = *reinterpret_cast<const short8*>(&As[arow * 256 + (kof ^ swz)]);
#pragma unroll
      for (int cf = 0; cf < 4; cf++) {
        short8 bf = *reinterpret_cast<const short8*>(&Wb[(cf * 8 + ks) * 512 + lane * 8]);
        acc[cf] = __builtin_amdgcn_mfma_f32_16x16x32_bf16(af, bf, acc[cf], 0, 0, 0);
      }
    }
    __builtin_amdgcn_s_setprio(0);
#pragma unroll
    for (int cf = 0; cf < 4; cf++) {
      int cg = h * 4 + cf;
      int c = cg * 16 + lr;
#pragma unroll
      for (int rg = 0; rg < 4; rg++) {
        int mrow = w * 16 + rb + rg;
        mt[mrow * 128 + (c ^ ((mrow & 7) << 3))] = f2b(e1[cg][rg] + acc[cf][rg] + mb2[c]);
      }
    }
  }

  __syncthreads();
#pragma unroll
  for (int p = 0; p < 4; p++) {
    int u = p * 256 + tid;
    int row = u >> 4, col8 = (u & 15) * 8;
    int gr = r0 + row;
    if (gr < RE_) {
      short8 v = *reinterpret_cast<const short8*>(&mt[row * 128 + (col8 ^ ((row & 7) << 3))]);
      __builtin_nontemporal_store(v, reinterpret_cast<short8*>(&eout[(size_t)gr * 128 + col8]));
    }
  }
}

// ---------------- head ----------------
__global__ void k_head(const float* __restrict__ node, const float* __restrict__ Wo1,
                       const float* __restrict__ bo1, const float* __restrict__ Wo2,
                       const float* __restrict__ bo2, float* __restrict__ out) {
  int b = blockIdx.x;
  int tid = threadIdx.x;  // 128
  __shared__ float gsh[D_];
  __shared__ float h1[D_];
  float s = 0.f;
  for (int n = 0; n < N_; n++) s += node[((size_t)b * N_ + n) * D_ + tid];
  gsh[tid] = s * (1.f / 67.f);
  __syncthreads();
  float a = 0.f;
  for (int k = 0; k < D_; k++) a += gsh[k] * Wo1[k * D_ + tid];
  h1[tid] = fmaxf(a + bo1[tid], 0.f);
  __syncthreads();
  if (tid < DOUT_) {
    float r = 0.f;
    for (int k = 0; k < D_; k++) r += h1[k] * Wo2[k * DOUT_ + tid];
    out[b * DOUT_ + tid] = r + bo2[tid];
  }
}

// ---------------- host ----------------
extern "C" void kernel_launch(void* const* d_in, const int* in_sizes, int n_in,
                              void* d_out, int out_size, void* d_ws, size_t ws_size,
                              hipStream_t stream) {
  const float* w0   = (const float*)d_in[0];
  const float* w1   = (const float*)d_in[1];
  const float* w2   = (const float*)d_in[2];
  const float* b0   = (const float*)d_in[3];
  const float* b1   = (const float*)d_in[4];
  const float* b2   = (const float*)d_in[5];
  const float* pwW  = (const float*)d_in[6];
  const float* pwb  = (const float*)d_in[7];
  const float* pbW  = (const float*)d_in[8];
  const float* pbb  = (const float*)d_in[9];
  const float* niW  = (const float*)d_in[10];
  const float* nib  = (const float*)d_in[11];
  const float* eiW  = (const float*)d_in[12];
  const float* eib  = (const float*)d_in[13];
  const float* pos  = (const float*)d_in[14];
  const float* alng = (const float*)d_in[15];
  const float* alnb = (const float*)d_in[16];
  const float* Wqkvn= (const float*)d_in[17];
  const float* Wqkve= (const float*)d_in[18];
  const float* Wao  = (const float*)d_in[19];
  const float* bao  = (const float*)d_in[20];
  const float* Wl0  = (const float*)d_in[21];
  const float* bl0  = (const float*)d_in[22];
  const float* nlng = (const float*)d_in[23];
  const float* nlnb = (const float*)d_in[24];
  const float* nW1  = (const float*)d_in[25];
  const float* nb1  = (const float*)d_in[26];
  const float* nW2  = (const float*)d_in[27];
  const float* nb2  = (const float*)d_in[28];
  const float* elng = (const float*)d_in[29];
  const float* elnb = (const float*)d_in[30];
  const float* We   = (const float*)d_in[31];
  const float* be   = (const float*)d_in[32];
  const float* Ws   = (const float*)d_in[33];
  const float* bs   = (const float*)d_in[34];
  const float* Wt   = (const float*)d_in[35];
  const float* bt   = (const float*)d_in[36];
  const float* Wer  = (const float*)d_in[37];
  const float* Wec  = (const float*)d_in[38];
  const float* We1  = (const float*)d_in[39];
  const float* be1  = (const float*)d_in[40];
  const float* Wel0 = (const float*)d_in[41];
  const float* bel0 = (const float*)d_in[42];
  const float* mlng = (const float*)d_in[43];
  const float* mlnb = (const float*)d_in[44];
  const float* mW1  = (const float*)d_in[45];
  const float* mb1  = (const float*)d_in[46];
  const float* mW2  = (const float*)d_in[47];
  const float* mb2  = (const float*)d_in[48];
  const float* Wo1  = (const float*)d_in[49];
  const float* bo1  = (const float*)d_in[50];
  const float* Wo2  = (const float*)d_in[51];
  const float* bo2  = (const float*)d_in[52];
  float* outp = (float*)d_out;

  const size_t E = (size_t)RE_ * D_;
  const size_t NODE = (size_t)RN_ * D_;
  const int DD = D_ * D_;

  float* ws = (float*)d_ws;
  size_t off = 0;
  auto alloc = [&](size_t nf) { float* p = ws + off; off += nf; return p; };
  ushort* edgeA = (ushort*)alloc(E / 2);
  ushort* edgeB = (ushort*)alloc(E / 2);
  float* stats = alloc(2 * (size_t)RE_);
  float* node  = alloc(NODE);
  float* qkvn  = alloc(3 * NODE);
  float* obuf  = alloc(NODE);
  float* rmean = alloc(NODE);
  float* cmean = alloc(NODE);
  float* rvec  = alloc(NODE);
  float* cvec  = alloc(NODE);
  float* WcN   = alloc((size_t)L_ * DD);
  float* bcN   = alloc((size_t)L_ * D_);
  float* WcE   = alloc((size_t)L_ * DD);
  float* bcE   = alloc((size_t)L_ * D_);
  float* vecs  = alloc(4 * D_);
  ushort* wbf   = (ushort*)alloc(245760);
  ushort* wq_fm = wbf;
  ushort* we_fm = wq_fm + (size_t)L_ * 49152;
  ushort* wce_fm= we_fm + (size_t)L_ * 32768;
  ushort* w1_fm = wce_fm + (size_t)L_ * 16384;
  ushort* w2_fm = w1_fm + (size_t)L_ * 32768;
  (void)ws_size; (void)in_sizes; (void)n_in; (void)out_size;

  k_comb<<<(2 * L_ * DD + 255) / 256, 256, 0, stream>>>(Wao, bao, Wl0, bl0, We1, be1, Wel0, bel0,
                                                        WcN, bcN, WcE, bcE);
  k_prepw<<<1920, 256, 0, stream>>>(Wqkve, We, WcE, mW1, mW2, wq_fm, we_fm, wce_fm, w1_fm, w2_fm);
  k_vecs<<<1, 128, 0, stream>>>(pbW, pbb, niW, nib, pwW, pwb, eiW, eib, vecs);
  k_init_node<<<(RN_ * D_ + 255) / 256, 256, 0, stream>>>(b0, b1, b2, vecs, pos, node);
  k_init_edge<<<(int)((E + 255) / 256), 256, 0, stream>>>(w0, w1, w2, vecs, edgeA);

  const int GE = (RE_ + 63) / 64;  // 2245
  const int GN = (RN_ + 63) / 64;  // 34
  const int GM = RN_ / 16;         // 134

  for (int l = 0; l < L_; l++) {
    ushort* ein  = (l & 1) ? edgeB : edgeA;
    ushort* eout = (l & 1) ? edgeA : edgeB;
    const float* Wqn = Wqkvn + (size_t)l * D_ * 384;

    k_lnqkv<<<dim3(GN, 6), 256, 0, stream>>>(node, alng + l * D_, alnb + l * D_, Wqn, qkvn);
    k_eattn<<<RN_, 256, 0, stream>>>(ein, qkvn, wq_fm + (size_t)l * 49152,
                                     elng + l * D_, elnb + l * D_, stats, rmean, obuf);
    k_nodemlp<<<GM, 256, 0, stream>>>(node, obuf, WcN + (size_t)l * DD, bcN + l * D_,
                                      nlng + l * D_, nlnb + l * D_,
                                      nW1 + (size_t)l * D_ * 256, nb1 + l * 256,
                                      nW2 + (size_t)l * 256 * D_, nb2 + l * D_);

    k_colmean<<<RN_, 128, 0, stream>>>(ein, stats, elng + l * D_, elnb + l * D_, cmean);
    k_nvec<<<dim3(GN, 2, 2), 256, 0, stream>>>(node, rmean, cmean,
                                               Ws + (size_t)l * DD, Wer + (size_t)l * DD,
                                               Wt + (size_t)l * DD, Wec + (size_t)l * DD,
                                               bs + l * D_, be + l * D_, bt + l * D_,
                                               rvec, cvec);

    k_fedge<<<GE, 256, 0, stream>>>(ein, eout, stats,
                                    elng + l * D_, elnb + l * D_,
                                    we_fm + (size_t)l * 32768, rvec, cvec,
                                    wce_fm + (size_t)l * 16384, bcE + l * D_,
                                    mlng + l * D_, mlnb + l * D_,
                                    w1_fm + (size_t)l * 32768, mb1 + l * 256,
                                    w2_fm + (size_t)l * 32768, mb2 + l * D_);
  }

  k_head<<<B_, 128, 0, stream>>>(node, Wo1, bo1, Wo2, bo2, outp);
}

// Round 16
// 997.203 us; speedup vs baseline: 1.3079x; 1.0065x over previous
//
#include <hip/hip_runtime.h>
#include <math.h>

constexpr int B_ = 32, N_ = 67, D_ = 128, H_ = 8, DH_ = 16, L_ = 3;
constexpr int NN_ = N_ * N_;          // 4489
constexpr int RN_ = B_ * N_;          // 2144
constexpr int RE_ = B_ * NN_;         // 143648
constexpr int DOUT_ = 10;

typedef __attribute__((ext_vector_type(8))) short short8;
typedef __attribute__((ext_vector_type(4))) float f32x4;

// branchless tanh-approx GELU (max abs err ~3e-4; downstream-amplified ~1e-4 << 1.5e-3 tol)
__device__ __forceinline__ float gelu_f(float x) {
  float u = x * (0.7978845608028654f + 0.035677408136f * x * x);
  float e = __expf(-2.f * u);
  return x * (1.f / (1.f + e));   // 0.5x(1+tanh(u)) == x*sigmoid(2u)
}
__device__ __forceinline__ ushort f2b(float x) {
  union { float f; unsigned u; } v; v.f = x;
  return (ushort)((v.u + 0x7FFFu + ((v.u >> 16) & 1u)) >> 16);
}
__device__ __forceinline__ float b2f(ushort u) {
  union { unsigned u; float f; } v; v.u = (unsigned)u << 16; return v.f;
}

// ---------------- precompute: combined weights (Wao@Wl0, We1@Wel0) ----------------
__global__ void k_comb(const float* __restrict__ Wao, const float* __restrict__ bao,
                       const float* __restrict__ Wl0, const float* __restrict__ bl0,
                       const float* __restrict__ We1, const float* __restrict__ be1,
                       const float* __restrict__ Wel0, const float* __restrict__ bel0,
                       float* WcN, float* bcN, float* WcE, float* bcE) {
  int t = blockIdx.x * blockDim.x + threadIdx.x;
  const int half = L_ * D_ * D_;
  if (t >= 2 * half) return;
  int which = t / half;
  int u = t - which * half;
  int l = u / (D_ * D_);
  int ij = u - l * (D_ * D_);
  int i = ij >> 7, j = ij & 127;
  const float* A  = (which == 0 ? Wao : We1) + (size_t)l * D_ * D_;
  const float* Bm = (which == 0 ? Wl0 : Wel0) + (size_t)l * D_ * D_;
  float s = 0.f;
  for (int k = 0; k < D_; k++) s += A[i * D_ + k] * Bm[k * D_ + j];
  if (which == 0) WcN[u] = s; else WcE[u] = s;
  if (i == 0) {
    const float* ba = (which == 0 ? bao : be1) + l * D_;
    const float* bl = (which == 0 ? bl0 : bel0) + l * D_;
    float sb = 0.f;
    for (int k = 0; k < D_; k++) sb += ba[k] * Bm[k * D_ + j];
    if (which == 0) bcN[l * D_ + j] = sb + bl[j]; else bcE[l * D_ + j] = sb + bl[j];
  }
}

// ---------------- precompute: fragment-major bf16 weights ----------------
__device__ __forceinline__ float enc_src(const float* src, int K, int C, int NKS, int r, int l) {
  int frag = r >> 9;
  int within = r & 511;
  int lane = within >> 3, j = within & 7;
  int cf = frag / NKS, ks = frag - cf * NKS;
  int k = ks * 32 + (lane >> 4) * 8 + j;
  int c = cf * 16 + (lane & 15);
  return src[(size_t)l * K * C + (size_t)k * C + c];
}

__global__ void k_prepw(const float* __restrict__ Wqkve, const float* __restrict__ We,
                        const float* __restrict__ WcE, const float* __restrict__ mW1,
                        const float* __restrict__ mW2,
                        ushort* wq, ushort* we, ushort* wce, ushort* w1, ushort* w2) {
  int t = blockIdx.x * 256 + threadIdx.x;
  const int S0 = L_ * 49152, S1 = L_ * 32768, S2 = L_ * 16384, S3 = L_ * 32768, S4 = L_ * 32768;
  if (t < S0) { int l = t / 49152, r = t % 49152; wq[t]  = f2b(enc_src(Wqkve, 128, 384, 4, r, l)); return; }
  t -= S0;
  if (t < S1) { int l = t / 32768, r = t % 32768; we[t]  = f2b(enc_src(We,   256, 128, 8, r, l)); return; }
  t -= S1;
  if (t < S2) { int l = t / 16384, r = t % 16384; wce[t] = f2b(enc_src(WcE,  128, 128, 4, r, l)); return; }
  t -= S2;
  if (t < S3) { int l = t / 32768, r = t % 32768; w1[t]  = f2b(enc_src(mW1,  128, 256, 4, r, l)); return; }
  t -= S3;
  if (t < S4) { int l = t / 32768, r = t % 32768; w2[t]  = f2b(enc_src(mW2,  256, 128, 8, r, l)); return; }
}

// ---------------- precompute: folded input-embed vectors ----------------
__global__ void k_vecs(const float* pbW, const float* pbb, const float* niW, const float* nib,
                       const float* pwW, const float* pwb, const float* eiW, const float* eib,
                       float* vecs) {
  int j = threadIdx.x;
  if (j >= D_) return;
  float u = 0, c = 0, v = 0, ce = 0;
  for (int k = 0; k < D_; k++) {
    u  += pbW[k] * niW[k * D_ + j];
    c  += pbb[k] * niW[k * D_ + j];
    v  += pwW[k] * eiW[k * D_ + j];
    ce += pwb[k] * eiW[k * D_ + j];
  }
  vecs[j] = u; vecs[D_ + j] = c + nib[j]; vecs[2 * D_ + j] = v; vecs[3 * D_ + j] = ce + eib[j];
}

// ---------------- init node / edge ----------------
__global__ void k_init_node(const float* __restrict__ b0, const float* __restrict__ b1,
                            const float* __restrict__ b2, const float* __restrict__ vecs,
                            const float* __restrict__ pos, float* __restrict__ node) {
  int idx = blockIdx.x * blockDim.x + threadIdx.x;
  if (idx >= RN_ * D_) return;
  int r = idx >> 7, d = idx & 127;
  int b = r / N_, n = r - b * N_;
  float nf = 0.f;
  if (n >= 2 && n < 34)       nf = b0[b * 32 + n - 2];
  else if (n >= 34 && n < 66) nf = b1[b * 32 + n - 34];
  else if (n == 66)           nf = b2[b];
  int pr = (n == 0) ? 0 : (n == 1) ? 1 : (n < 34) ? 2 : (n < 66) ? 3 : 4;
  node[idx] = nf * vecs[d] + vecs[D_ + d] + pos[pr * D_ + d];
}

__global__ void k_init_edge(const float* __restrict__ w0, const float* __restrict__ w1,
                            const float* __restrict__ w2, const float* __restrict__ vecs,
                            ushort* __restrict__ edge) {
  int idx = blockIdx.x * blockDim.x + threadIdx.x;
  if (idx >= RE_ * D_) return;
  int r = idx >> 7, d = idx & 127;
  int b = r / NN_;
  int rem = r - b * NN_;
  int n = rem / N_, m = rem - n * N_;
  float ef = 0.f;
  if (n < 2)        { if (m >= 2 && m < 34)  ef = w0[(b * 2 + n) * 32 + (m - 2)]; }
  else if (n < 34)  { if (m >= 34 && m < 66) ef = w1[(b * 32 + (n - 2)) * 32 + (m - 34)]; }
  else if (n < 66)  { if (m == 66)           ef = w2[b * 32 + (n - 34)]; }
  edge[idx] = f2b(ef * vecs[2 * D_ + d] + vecs[3 * D_ + d]);
}

// ---------------- fused node LN + QKV projection (no bias) ----------------
__global__ __launch_bounds__(256) void k_lnqkv(
    const float* __restrict__ node, const float* __restrict__ g, const float* __restrict__ bb,
    const float* __restrict__ W, float* __restrict__ out) {
  __shared__ float As[16][68];
  __shared__ float Wsh[16][68];
  __shared__ float stmu[64], strs[64];
  int r0 = blockIdx.x * 64, c0 = blockIdx.y * 64;
  int tid = threadIdx.x;
  // per-row LN stats (4 threads / row)
  {
    int row = tid >> 2, part = tid & 3;
    int gr = r0 + row;
    int grc = (gr < RN_) ? gr : 0;
    const float* x = node + (size_t)grc * 128 + part * 32;
    float s = 0.f, q = 0.f;
#pragma unroll
    for (int i = 0; i < 8; i++) {
      float4 v = *reinterpret_cast<const float4*>(&x[i * 4]);
      s += v.x + v.y + v.z + v.w;
      q += v.x * v.x + v.y * v.y + v.z * v.z + v.w * v.w;
    }
    for (int o = 1; o < 4; o <<= 1) { s += __shfl_xor(s, o); q += __shfl_xor(q, o); }
    if (part == 0) {
      float mu = s * (1.f / 128.f);
      stmu[row] = mu;
      strs[row] = rsqrtf(q * (1.f / 128.f) - mu * mu + 1e-5f);
    }
  }
  __syncthreads();
  int tr = tid >> 4, tc = tid & 15;
  float acc[4][4] = {};
  for (int kk = 0; kk < 128; kk += 16) {
#pragma unroll
    for (int i = 0; i < 4; i++) {
      int lin = tid + i * 256;
      int r_in = lin >> 4, k_in = lin & 15;
      int r = r0 + r_in;
      float v = 0.f;
      if (r < RN_) {
        int k = kk + k_in;
        v = (node[(size_t)r * 128 + k] - stmu[r_in]) * strs[r_in] * g[k] + bb[k];
      }
      As[k_in][r_in] = v;
    }
#pragma unroll
    for (int i = 0; i < 4; i++) {
      int lin = tid + i * 256;
      int k_in = lin >> 6, c_in = lin & 63;
      Wsh[k_in][c_in] = W[(size_t)(kk + k_in) * 384 + c0 + c_in];
    }
    __syncthreads();
#pragma unroll
    for (int k = 0; k < 16; k++) {
      float4 a4 = *reinterpret_cast<const float4*>(&As[k][tr * 4]);
      float4 b4 = *reinterpret_cast<const float4*>(&Wsh[k][tc * 4]);
      float av[4] = {a4.x, a4.y, a4.z, a4.w};
      float bv[4] = {b4.x, b4.y, b4.z, b4.w};
#pragma unroll
      for (int i = 0; i < 4; i++)
#pragma unroll
        for (int j = 0; j < 4; j++) acc[i][j] += av[i] * bv[j];
    }
    __syncthreads();
  }
#pragma unroll
  for (int i = 0; i < 4; i++) {
    int r = r0 + tr * 4 + i;
    if (r >= RN_) continue;
#pragma unroll
    for (int j = 0; j < 4; j++) {
      int c = c0 + tc * 4 + j;
      out[(size_t)r * 384 + c] = acc[i][j];
    }
  }
}

// ---------------- fused node residual + MLP ----------------
__global__ __launch_bounds__(256) void k_nodemlp(
    float* __restrict__ node, const float* __restrict__ obuf,
    const float* __restrict__ WcN, const float* __restrict__ bcN,
    const float* __restrict__ g, const float* __restrict__ bb,
    const float* __restrict__ nW1, const float* __restrict__ nb1,
    const float* __restrict__ nW2, const float* __restrict__ nb2) {
  __shared__ float As[16][17];
  __shared__ float Wsh[16][132];
  __shared__ ushort Hs[16][136];
  __shared__ ushort Ts[16][264];
  int r0 = blockIdx.x * 16;
  int tid = threadIdx.x;
  int tr = tid >> 4, tc = tid & 15;     // row tr, 8-col group tc
  size_t grow = (size_t)(r0 + tr) * 128;

  auto stageW = [&](const float* src, int ld, int kk, int cbase) {
    int k = tid & 15, cp = tid >> 4;
    const float* s = &src[(size_t)(kk + k) * ld + cbase + cp * 8];
    float* d = &Wsh[k][cp * 8];
#pragma unroll
    for (int j = 0; j < 8; j++) d[j] = s[j];
  };

  // phase 1: acc = obuf @ WcN (K=128)
  float acc[8] = {};
  for (int kk = 0; kk < 128; kk += 16) {
    As[tr][tc] = obuf[grow + kk + tc];
    stageW(WcN, 128, kk, 0);
    __syncthreads();
#pragma unroll
    for (int k = 0; k < 16; k++) {
      float a = As[tr][k];
#pragma unroll
      for (int j = 0; j < 8; j++) acc[j] += a * Wsh[k][tc * 8 + j];
    }
    __syncthreads();
  }
  // phase 2: nd = node + acc + bcN ; LN -> Hs (bf16)
  float nd[8];
  float s = 0.f, q = 0.f;
#pragma unroll
  for (int j = 0; j < 8; j++) {
    int c = tc * 8 + j;
    float v = node[grow + c] + acc[j] + bcN[c];
    nd[j] = v; s += v; q += v * v;
  }
  for (int o = 1; o < 16; o <<= 1) { s += __shfl_xor(s, o); q += __shfl_xor(q, o); }
  float mu = s * (1.f / 128.f);
  float rs = rsqrtf(q * (1.f / 128.f) - mu * mu + 1e-5f);
#pragma unroll
  for (int j = 0; j < 8; j++) {
    int c = tc * 8 + j;
    Hs[tr][c] = f2b((nd[j] - mu) * rs * g[c] + bb[c]);
  }
  // phase 3: Ts = gelu(Hs @ nW1 + nb1), C=256 in 2 halves of 128
  for (int ch = 0; ch < 2; ch++) {
    float a2[8] = {};
    for (int kk = 0; kk < 128; kk += 16) {
      __syncthreads();
      stageW(nW1, 256, kk, ch * 128);
      __syncthreads();
#pragma unroll
      for (int k = 0; k < 16; k++) {
        float a = b2f(Hs[tr][kk + k]);
#pragma unroll
        for (int j = 0; j < 8; j++) a2[j] += a * Wsh[k][tc * 8 + j];
      }
    }
#pragma unroll
    for (int j = 0; j < 8; j++) {
      int c = ch * 128 + tc * 8 + j;
      Ts[tr][c] = f2b(gelu_f(a2[j] + nb1[c]));
    }
  }
  // phase 4: node = nd + Ts @ nW2 + nb2 (K=256)
  float a3[8] = {};
  for (int kk = 0; kk < 256; kk += 16) {
    __syncthreads();
    stageW(nW2, 128, kk, 0);
    __syncthreads();
#pragma unroll
    for (int k = 0; k < 16; k++) {
      float a = b2f(Ts[tr][kk + k]);
#pragma unroll
      for (int j = 0; j < 8; j++) a3[j] += a * Wsh[k][tc * 8 + j];
    }
  }
#pragma unroll
  for (int j = 0; j < 8; j++) {
    int c = tc * 8 + j;
    node[grow + c] = nd[j] + a3[j] + nb2[c];
  }
}

// ---------------- fused rvec/cvec: out = node@W1 + A2@W2 + bias ----------------
__global__ __launch_bounds__(256) void k_nvec(
    const float* __restrict__ node, const float* __restrict__ rmean, const float* __restrict__ cmean,
    const float* __restrict__ Ws, const float* __restrict__ Wer,
    const float* __restrict__ Wt, const float* __restrict__ Wec,
    const float* __restrict__ bs, const float* __restrict__ be, const float* __restrict__ bt,
    float* __restrict__ rvec, float* __restrict__ cvec) {
  __shared__ float Ash[16][68];
  __shared__ float Wsh[16][68];
  int which = blockIdx.z;
  const float* A2 = which ? cmean : rmean;
  const float* W1 = which ? Wt : Ws;
  const float* W2 = which ? Wec : Wer;
  float* out = which ? cvec : rvec;
  int r0 = blockIdx.x * 64, c0 = blockIdx.y * 64;
  int tid = threadIdx.x, tr = tid >> 4, tc = tid & 15;
  float acc[4][4] = {};
  for (int kk = 0; kk < 256; kk += 16) {
#pragma unroll
    for (int i = 0; i < 4; i++) {
      int lin = tid + i * 256;
      int r_in = lin >> 4, k_in = lin & 15;
      int r = r0 + r_in, k = kk + k_in;
      float v = 0.f;
      if (r < RN_) v = (k < 128) ? node[(size_t)r * 128 + k] : A2[(size_t)r * 128 + (k - 128)];
      Ash[k_in][r_in] = v;
    }
#pragma unroll
    for (int i = 0; i < 4; i++) {
      int lin = tid + i * 256;
      int k_in = lin >> 6, c_in = lin & 63;
      int k = kk + k_in, c = c0 + c_in;
      Wsh[k_in][c_in] = (k < 128) ? W1[(size_t)k * 128 + c] : W2[(size_t)(k - 128) * 128 + c];
    }
    __syncthreads();
#pragma unroll
    for (int k = 0; k < 16; k++) {
      float4 a4 = *reinterpret_cast<const float4*>(&Ash[k][tr * 4]);
      float4 b4 = *reinterpret_cast<const float4*>(&Wsh[k][tc * 4]);
      float av[4] = {a4.x, a4.y, a4.z, a4.w};
      float bv[4] = {b4.x, b4.y, b4.z, b4.w};
#pragma unroll
      for (int i = 0; i < 4; i++)
#pragma unroll
        for (int j = 0; j < 4; j++) acc[i][j] += av[i] * bv[j];
    }
    __syncthreads();
  }
#pragma unroll
  for (int i = 0; i < 4; i++) {
    int r = r0 + tr * 4 + i;
    if (r >= RN_) continue;
#pragma unroll
    for (int j = 0; j < 4; j++) {
      int c = c0 + tc * 4 + j;
      float bias = which ? bt[c] : (bs[c] + be[c]);
      out[(size_t)r * 128 + c] = acc[i][j] + bias;
    }
  }
}

// ---------------- fused per-(b,n) attention + edge LN stats + rowmean ----------------
__global__ __launch_bounds__(256, 3) void k_eattn(
    const ushort* __restrict__ edge, const float* __restrict__ qkvn,
    const ushort* __restrict__ wqf,   // fragment-major [24cf][4ks][64][8]
    const float* __restrict__ gE, const float* __restrict__ bE,
    float* __restrict__ stats, float* __restrict__ rmean,
    float* __restrict__ obuf) {
  __shared__ __align__(16) ushort ed[68 * 128];   // 17.4 KB
  __shared__ __align__(16) ushort Eb[68 * 202];   // 27.5 KB
  __shared__ float qn_s[384];
  __shared__ float sc[4][68];
  __shared__ float red[4][16][4];
  __shared__ float stmu[68], strs[68];
  int bn = blockIdx.x;
  int b = bn / N_;
  int tid = threadIdx.x;
  int w = tid >> 6, lane = tid & 63, lr = lane & 15, lk8 = (lane >> 4) * 8;
  int swz = (lr & 7) << 3;
  int rb = (lane >> 4) * 4;
  size_t ebase = (size_t)bn * N_ * 128;

  // stage bf16 edge tile (NT: single-use stream here) + per-row LN stats
  for (int i = 0; i < 5; i++) {
    int u = tid + i * 256;
    if (u < 67 * 16) {
      int row = u >> 4, k8 = (u & 15) * 8;
      short8 t = __builtin_nontemporal_load(
          reinterpret_cast<const short8*>(&edge[ebase + (size_t)row * 128 + k8]));
      *reinterpret_cast<short8*>(&ed[row * 128 + (k8 ^ ((row & 7) << 3))]) = t;
      float s = 0.f, q = 0.f;
#pragma unroll
      for (int j = 0; j < 8; j++) { float v = b2f((ushort)t[j]); s += v; q += v * v; }
      for (int o = 8; o; o >>= 1) { s += __shfl_xor(s, o); q += __shfl_xor(q, o); }
      if ((u & 15) == 0) {
        float mu = s * (1.f / 128.f);
        float rs = rsqrtf(q * (1.f / 128.f) - mu * mu + 1e-5f);
        stmu[row] = mu; strs[row] = rs;
        stats[2 * (size_t)(bn * N_ + row)] = mu;
        stats[2 * (size_t)(bn * N_ + row) + 1] = rs;
      }
    }
  }
  for (int i = tid; i < 384; i += 256) qn_s[i] = qkvn[(size_t)bn * 384 + i];
  __syncthreads();
  // rowmean of LN(edge)
  if (tid < 128) {
    float s = 0.f;
    for (int m = 0; m < 67; m++)
      s += (b2f(ed[m * 128 + (tid ^ ((m & 7) << 3))]) - stmu[m]) * strs[m];
    rmean[(size_t)bn * 128 + tid] = gE[tid] * (s * (1.f / 67.f)) + bE[tid];
  }

  // 2 chunks of 192 cols (4 heads each); wave w = head (ch*4 + w)
  for (int ch = 0; ch < 2; ch++) {
    int h0 = ch * 4;
    f32x4 acc[5][3] = {};
    __builtin_amdgcn_s_setprio(1);
#pragma unroll
    for (int ks = 0; ks < 4; ks++) {
      int kof = ks * 32 + lk8;
      short8 af[5];
#pragma unroll
      for (int rf = 0; rf < 5; rf++)
        af[rf] = *reinterpret_cast<const short8*>(&ed[(rf * 16 + lr) * 128 + (kof ^ swz)]);
#pragma unroll
      for (int cl = 0; cl < 3; cl++) {
        short8 bf = *reinterpret_cast<const short8*>(
            &wqf[(size_t)(((ch * 12 + w * 3 + cl) * 4 + ks) * 64 + lane) * 8]);
#pragma unroll
        for (int rf = 0; rf < 5; rf++)
          acc[rf][cl] = __builtin_amdgcn_mfma_f32_16x16x32_bf16(af[rf], bf, acc[rf][cl], 0, 0, 0);
      }
    }
    __builtin_amdgcn_s_setprio(0);
#pragma unroll
    for (int rf = 0; rf < 5; rf++)
#pragma unroll
      for (int cl = 0; cl < 3; cl++) {
        int colc = (w * 3 + cl) * 16 + lr;
#pragma unroll
        for (int rg = 0; rg < 4; rg++) {
          int er = rf * 16 + rb + rg;
          if (er < 67) Eb[er * 202 + colc] = f2b(acc[rf][cl][rg]);
        }
      }
    __syncthreads();
    // scores (4 heads x 67)
    for (int idx = tid; idx < 268; idx += 256) {
      int h2 = idx / 67, m = idx - h2 * 67;
      const ushort* e = &Eb[m * 202 + h2 * 48];
      const float* kn = &qkvn[(size_t)(b * N_ + m) * 384 + (h0 + h2) * 48 + 16];
      const float* qn = &qn_s[(h0 + h2) * 48];
      float s2 = 0.f;
#pragma unroll
      for (int d = 0; d < 16; d++)
        s2 += (qn[d] + b2f(e[d])) * (kn[d] + b2f(e[16 + d]));
      sc[h2][m] = s2 * 0.25f;
    }
    __syncthreads();
    // softmax: wave w -> head w of chunk
    {
      float v0 = (lane < 67) ? sc[w][lane] : -1e30f;
      float v1 = (lane < 3) ? sc[w][lane + 64] : -1e30f;
      float mx = fmaxf(v0, v1);
      for (int o = 32; o; o >>= 1) mx = fmaxf(mx, __shfl_xor(mx, o));
      float e0 = (lane < 67) ? __expf(v0 - mx) : 0.f;
      float e1 = (lane < 3) ? __expf(v1 - mx) : 0.f;
      float ss = e0 + e1;
      for (int o = 32; o; o >>= 1) ss += __shfl_xor(ss, o);
      float inv = 1.f / ss;
      if (lane < 67) sc[w][lane] = e0 * inv;
      if (lane < 3) sc[w][lane + 64] = e1 * inv;
    }
    __syncthreads();
    // PV
    {
      int item = tid >> 2, c = tid & 3;
      int h2 = item >> 4, d = item & 15;
      float p = 0.f;
      for (int m = c; m < 67; m += 4) {
        float v = qkvn[(size_t)(b * N_ + m) * 384 + (h0 + h2) * 48 + 32 + d]
                + b2f(Eb[m * 202 + h2 * 48 + 32 + d]);
        p += sc[h2][m] * v;
      }
      red[h2][d][c] = p;
    }
    __syncthreads();
    if (tid < 64) {
      int h2 = tid >> 4, d = tid & 15;
      obuf[(size_t)bn * 128 + (h0 + h2) * 16 + d] =
          red[h2][d][0] + red[h2][d][1] + red[h2][d][2] + red[h2][d][3];
    }
    __syncthreads();
  }
}

// ---------------- col means of LN(edge) ----------------
__global__ void k_colmean(const ushort* __restrict__ edge, const float* __restrict__ stats,
                          const float* __restrict__ g, const float* __restrict__ bb,
                          float* __restrict__ cmean) {
  int bm = blockIdx.x;
  int b = bm / N_, m = bm - b * N_;
  int d = threadIdx.x;
  float s = 0.f;
  for (int n = 0; n < N_; n++) {
    size_t r = (size_t)b * NN_ + (size_t)n * N_ + m;
    s += (b2f(edge[r * D_ + d]) - stats[2 * r]) * stats[2 * r + 1];
  }
  cmean[(size_t)bm * D_ + d] = g[d] * (s * (1.f / 67.f)) + bb[d];
}

// ---------------- fully-fused edge block: LDS-staged frag-major weights ----------------
__global__ __launch_bounds__(256, 2) void k_fedge(
    const ushort* __restrict__ ein, ushort* __restrict__ eout,
    const float* __restrict__ stats,
    const float* __restrict__ gE, const float* __restrict__ bE,
    const ushort* __restrict__ wef,
    const float* __restrict__ rvec, const float* __restrict__ cvec,
    const ushort* __restrict__ wcef,
    const float* __restrict__ bcE,
    const float* __restrict__ gM, const float* __restrict__ bM,
    const ushort* __restrict__ w1f,
    const float* __restrict__ mb1,
    const ushort* __restrict__ w2f,
    const float* __restrict__ mb2) {
  __shared__ __align__(16) ushort As[64 * 256];
  __shared__ __align__(16) ushort mt[64 * 128];
  __shared__ __align__(16) ushort Wb[32 * 512];
  int tid = threadIdx.x;
  int r0 = blockIdx.x * 64;
  int w = tid >> 6, lane = tid & 63, lr = lane & 15, lk8 = (lane >> 4) * 8;
  int swz = (lr & 7) << 3;
  int rb = (lane >> 4) * 4;
  int arow = w * 16 + lr;

  // weight chunk staging via direct global->LDS DMA (linear dest = base + lane*16B)
  auto stageW = [&](const ushort* src) {
#pragma unroll
    for (int i = 0; i < 8; i++) {
      int u = tid + i * 256;
      __builtin_amdgcn_global_load_lds(
          (const __attribute__((address_space(1))) unsigned int*)(src + (size_t)u * 8),
          (__attribute__((address_space(3))) unsigned int*)(&Wb[u * 8]),
          16, 0, 0);
    }
  };

#pragma unroll
  for (int i = 0; i < 8; i++) {
    int u = tid + i * 256;
    int row = u >> 5, c8 = (u & 31) * 8;
    int gr = r0 + row;
    int grc = (gr < RE_) ? gr : 0;
    int cc = c8 & 127;
    short8 t;
    float mu, rs;
    if (c8 < 128) {
      size_t srow = (size_t)grc;
      mu = stats[2 * srow]; rs = stats[2 * srow + 1];
      t = *reinterpret_cast<const short8*>(&ein[srow * 128 + cc]);
    } else {
      int b = grc / NN_; int rem = grc - b * NN_;
      int n = rem / N_, m = rem - n * N_;
      size_t srow = (size_t)b * NN_ + (size_t)m * N_ + n;
      mu = stats[2 * srow]; rs = stats[2 * srow + 1];
      t = __builtin_nontemporal_load(reinterpret_cast<const short8*>(&ein[srow * 128 + cc]));
    }
    short8 r8;
#pragma unroll
    for (int j = 0; j < 8; j++) {
      float v = (b2f((ushort)t[j]) - mu) * rs * gE[cc + j] + bE[cc + j];
      r8[j] = (short)f2b(v);
    }
    *reinterpret_cast<short8*>(&As[row * 256 + (c8 ^ ((row & 7) << 3))]) = r8;
  }
  int rvb[4], cvb[4], grows[4]; bool vr[4];
#pragma unroll
  for (int rg = 0; rg < 4; rg++) {
    int gr = r0 + w * 16 + rb + rg;
    vr[rg] = gr < RE_;
    int grc = vr[rg] ? gr : 0;
    grows[rg] = grc;
    int b = grc / NN_; int rem = grc - b * NN_;
    int n = rem / N_, m = rem - n * N_;
    rvb[rg] = (b * N_ + n) * 128;
    cvb[rg] = (b * N_ + m) * 128;
  }
  __syncthreads();

  for (int h = 0; h < 2; h++) {
    if (h) __syncthreads();
    stageW(wef + (size_t)h * 32 * 512);
    __syncthreads();
    f32x4 acc[4] = {};
    __builtin_amdgcn_s_setprio(1);
#pragma unroll
    for (int ks = 0; ks < 8; ks++) {
      int kof = ks * 32 + lk8;
      short8 af = *reinterpret_cast<const short8*>(&As[arow * 256 + (kof ^ swz)]);
#pragma unroll
      for (int cf = 0; cf < 4; cf++) {
        short8 bf = *reinterpret_cast<const short8*>(&Wb[(cf * 8 + ks) * 512 + lane * 8]);
        acc[cf] = __builtin_amdgcn_mfma_f32_16x16x32_bf16(af, bf, acc[cf], 0, 0, 0);
      }
    }
    __builtin_amdgcn_s_setprio(0);
#pragma unroll
    for (int cf = 0; cf < 4; cf++) {
      int c = (h * 4 + cf) * 16 + lr;
#pragma unroll
      for (int rg = 0; rg < 4; rg++) {
        float v = acc[cf][rg] + rvec[rvb[rg] + c] + cvec[cvb[rg] + c];
        int mrow = w * 16 + rb + rg;
        mt[mrow * 128 + (c ^ ((mrow & 7) << 3))] = f2b(gelu_f(v));
      }
    }
  }

  __syncthreads();
  stageW(wcef);
  __syncthreads();
  f32x4 e1[8] = {};
  __builtin_amdgcn_s_setprio(1);
#pragma unroll
  for (int ks = 0; ks < 4; ks++) {
    int kof = ks * 32 + lk8;
    short8 af = *reinterpret_cast<const short8*>(&mt[arow * 128 + (kof ^ swz)]);
#pragma unroll
    for (int cf = 0; cf < 8; cf++) {
      short8 bf = *reinterpret_cast<const short8*>(&Wb[(cf * 4 + ks) * 512 + lane * 8]);
      e1[cf] = __builtin_amdgcn_mfma_f32_16x16x32_bf16(af, bf, e1[cf], 0, 0, 0);
    }
  }
  __builtin_amdgcn_s_setprio(0);
  {
    float sr[4] = {0, 0, 0, 0}, qr[4] = {0, 0, 0, 0};
#pragma unroll
    for (int cf = 0; cf < 8; cf++) {
      int c = cf * 16 + lr;
#pragma unroll
      for (int rg = 0; rg < 4; rg++) {
        float v = e1[cf][rg] + bcE[c] + b2f(ein[(size_t)grows[rg] * 128 + c]);
        e1[cf][rg] = v;
        sr[rg] += v; qr[rg] += v * v;
      }
    }
#pragma unroll
    for (int rg = 0; rg < 4; rg++) {
      float s = sr[rg], q = qr[rg];
      for (int o = 8; o; o >>= 1) { s += __shfl_xor(s, o); q += __shfl_xor(q, o); }
      float mu = s * (1.f / 128.f);
      float rs = rsqrtf(q * (1.f / 128.f) - mu * mu + 1e-5f);
#pragma unroll
      for (int cf = 0; cf < 8; cf++) {
        int c = cf * 16 + lr;
        int mrow = w * 16 + rb + rg;
        mt[mrow * 128 + (c ^ ((mrow & 7) << 3))] =
            f2b((e1[cf][rg] - mu) * rs * gM[c] + bM[c]);
      }
    }
  }

  for (int h = 0; h < 2; h++) {
    __syncthreads();
    stageW(w1f + (size_t)h * 32 * 512);
    __syncthreads();
    f32x4 acc[8] = {};
    __builtin_amdgcn_s_setprio(1);
#pragma unroll
    for (int ks = 0; ks < 4; ks++) {
      int kof = ks * 32 + lk8;
      short8 af = *reinterpret_cast<const short8*>(&mt[arow * 128 + (kof ^ swz)]);
#pragma unroll
      for (int cf = 0; cf < 8; cf++) {
        short8 bf = *reinterpret_cast<const short8*>(&Wb[(cf * 4 + ks) * 512 + lane * 8]);
        acc[cf] = __builtin_amdgcn_mfma_f32_16x16x32_bf16(af, bf, acc[cf], 0, 0, 0);
      }
    }
    __builtin_amdgcn_s_setprio(0);
#pragma unroll
    for (int cf = 0; cf < 8; cf++) {
      int c2 = (h * 8 + cf) * 16 + lr;
#pragma unroll
      for (int rg = 0; rg < 4; rg++) {
        int mrow = w * 16 + rb + rg;
        As[mrow * 256 + (c2 ^ ((mrow & 7) << 3))] = f2b(gelu_f(acc[cf][rg] + mb1[c2]));
      }
    }
  }

  for (int h = 0; h < 2; h++) {
    __syncthreads();
    stageW(w2f + (size_t)h * 32 * 512);
    __syncthreads();
    f32x4 acc[4] = {};
    __builtin_amdgcn_s_setprio(1);
#pragma unroll
    for (int ks = 0; ks < 8; ks++) {
      int kof = ks * 32 + lk8;
      short8 af = *reinterpret_cast<const short8*>(&As[arow * 256 + (kof ^ swz)]);
#pragma unroll
      for (int cf = 0; cf < 4; cf++) {
        short8 bf = *reinterpret_cast<const short8*>(&Wb[(cf * 8 + ks) * 512 + lane * 8]);
        acc[cf] = __builtin_amdgcn_mfma_f32_16x16x32_bf16(af, bf, acc[cf], 0, 0, 0);
      }
    }
    __builtin_amdgcn_s_setprio(0);
#pragma unroll
    for (int cf = 0; cf < 4; cf++) {
      int cg = h * 4 + cf;
      int c = cg * 16 + lr;
#pragma unroll
      for (int rg = 0; rg < 4; rg++) {
        int mrow = w * 16 + rb + rg;
        mt[mrow * 128 + (c ^ ((mrow & 7) << 3))] = f2b(e1[cg][rg] + acc[cf][rg] + mb2[c]);
      }
    }
  }

  __syncthreads();
#pragma unroll
  for (int p = 0; p < 4; p++) {
    int u = p * 256 + tid;
    int row = u >> 4, col8 = (u & 15) * 8;
    int gr = r0 + row;
    if (gr < RE_) {
      short8 v = *reinterpret_cast<const short8*>(&mt[row * 128 + (col8 ^ ((row & 7) << 3))]);
      __builtin_nontemporal_store(v, reinterpret_cast<short8*>(&eout[(size_t)gr * 128 + col8]));
    }
  }
}

// ---------------- head ----------------
__global__ void k_head(const float* __restrict__ node, const float* __restrict__ Wo1,
                       const float* __restrict__ bo1, const float* __restrict__ Wo2,
                       const float* __restrict__ bo2, float* __restrict__ out) {
  int b = blockIdx.x;
  int tid = threadIdx.x;  // 128
  __shared__ float gsh[D_];
  __shared__ float h1[D_];
  float s = 0.f;
  for (int n = 0; n < N_; n++) s += node[((size_t)b * N_ + n) * D_ + tid];
  gsh[tid] = s * (1.f / 67.f);
  __syncthreads();
  float a = 0.f;
  for (int k = 0; k < D_; k++) a += gsh[k] * Wo1[k * D_ + tid];
  h1[tid] = fmaxf(a + bo1[tid], 0.f);
  __syncthreads();
  if (tid < DOUT_) {
    float r = 0.f;
    for (int k = 0; k < D_; k++) r += h1[k] * Wo2[k * DOUT_ + tid];
    out[b * DOUT_ + tid] = r + bo2[tid];
  }
}

// ---------------- host ----------------
extern "C" void kernel_launch(void* const* d_in, const int* in_sizes, int n_in,
                              void* d_out, int out_size, void* d_ws, size_t ws_size,
                              hipStream_t stream) {
  const float* w0   = (const float*)d_in[0];
  const float* w1   = (const float*)d_in[1];
  const float* w2   = (const float*)d_in[2];
  const float* b0   = (const float*)d_in[3];
  const float* b1   = (const float*)d_in[4];
  const float* b2   = (const float*)d_in[5];
  const float* pwW  = (const float*)d_in[6];
  const float* pwb  = (const float*)d_in[7];
  const float* pbW  = (const float*)d_in[8];
  const float* pbb  = (const float*)d_in[9];
  const float* niW  = (const float*)d_in[10];
  const float* nib  = (const float*)d_in[11];
  const float* eiW  = (const float*)d_in[12];
  const float* eib  = (const float*)d_in[13];
  const float* pos  = (const float*)d_in[14];
  const float* alng = (const float*)d_in[15];
  const float* alnb = (const float*)d_in[16];
  const float* Wqkvn= (const float*)d_in[17];
  const float* Wqkve= (const float*)d_in[18];
  const float* Wao  = (const float*)d_in[19];
  const float* bao  = (const float*)d_in[20];
  const float* Wl0  = (const float*)d_in[21];
  const float* bl0  = (const float*)d_in[22];
  const float* nlng = (const float*)d_in[23];
  const float* nlnb = (const float*)d_in[24];
  const float* nW1  = (const float*)d_in[25];
  const float* nb1  = (const float*)d_in[26];
  const float* nW2  = (const float*)d_in[27];
  const float* nb2  = (const float*)d_in[28];
  const float* elng = (const float*)d_in[29];
  const float* elnb = (const float*)d_in[30];
  const float* We   = (const float*)d_in[31];
  const float* be   = (const float*)d_in[32];
  const float* Ws   = (const float*)d_in[33];
  const float* bs   = (const float*)d_in[34];
  const float* Wt   = (const float*)d_in[35];
  const float* bt   = (const float*)d_in[36];
  const float* Wer  = (const float*)d_in[37];
  const float* Wec  = (const float*)d_in[38];
  const float* We1  = (const float*)d_in[39];
  const float* be1  = (const float*)d_in[40];
  const float* Wel0 = (const float*)d_in[41];
  const float* bel0 = (const float*)d_in[42];
  const float* mlng = (const float*)d_in[43];
  const float* mlnb = (const float*)d_in[44];
  const float* mW1  = (const float*)d_in[45];
  const float* mb1  = (const float*)d_in[46];
  const float* mW2  = (const float*)d_in[47];
  const float* mb2  = (const float*)d_in[48];
  const float* Wo1  = (const float*)d_in[49];
  const float* bo1  = (const float*)d_in[50];
  const float* Wo2  = (const float*)d_in[51];
  const float* bo2  = (const float*)d_in[52];
  float* outp = (float*)d_out;

  const size_t E = (size_t)RE_ * D_;
  const size_t NODE = (size_t)RN_ * D_;
  const int DD = D_ * D_;

  float* ws = (float*)d_ws;
  size_t off = 0;
  auto alloc = [&](size_t nf) { float* p = ws + off; off += nf; return p; };
  ushort* edgeA = (ushort*)alloc(E / 2);
  ushort* edgeB = (ushort*)alloc(E / 2);
  float* stats = alloc(2 * (size_t)RE_);
  float* node  = alloc(NODE);
  float* qkvn  = alloc(3 * NODE);
  float* obuf  = alloc(NODE);
  float* rmean = alloc(NODE);
  float* cmean = alloc(NODE);
  float* rvec  = alloc(NODE);
  float* cvec  = alloc(NODE);
  float* WcN   = alloc((size_t)L_ * DD);
  float* bcN   = alloc((size_t)L_ * D_);
  float* WcE   = alloc((size_t)L_ * DD);
  float* bcE   = alloc((size_t)L_ * D_);
  float* vecs  = alloc(4 * D_);
  ushort* wbf   = (ushort*)alloc(245760);
  ushort* wq_fm = wbf;
  ushort* we_fm = wq_fm + (size_t)L_ * 49152;
  ushort* wce_fm= we_fm + (size_t)L_ * 32768;
  ushort* w1_fm = wce_fm + (size_t)L_ * 16384;
  ushort* w2_fm = w1_fm + (size_t)L_ * 32768;
  (void)ws_size; (void)in_sizes; (void)n_in; (void)out_size;

  k_comb<<<(2 * L_ * DD + 255) / 256, 256, 0, stream>>>(Wao, bao, Wl0, bl0, We1, be1, Wel0, bel0,
                                                        WcN, bcN, WcE, bcE);
  k_prepw<<<1920, 256, 0, stream>>>(Wqkve, We, WcE, mW1, mW2, wq_fm, we_fm, wce_fm, w1_fm, w2_fm);
  k_vecs<<<1, 128, 0, stream>>>(pbW, pbb, niW, nib, pwW, pwb, eiW, eib, vecs);
  k_init_node<<<(RN_ * D_ + 255) / 256, 256, 0, stream>>>(b0, b1, b2, vecs, pos, node);
  k_init_edge<<<(int)((E + 255) / 256), 256, 0, stream>>>(w0, w1, w2, vecs, edgeA);

  const int GE = (RE_ + 63) / 64;  // 2245
  const int GN = (RN_ + 63) / 64;  // 34
  const int GM = RN_ / 16;         // 134

  for (int l = 0; l < L_; l++) {
    ushort* ein  = (l & 1) ? edgeB : edgeA;
    ushort* eout = (l & 1) ? edgeA : edgeB;
    const float* Wqn = Wqkvn + (size_t)l * D_ * 384;

    k_lnqkv<<<dim3(GN, 6), 256, 0, stream>>>(node, alng + l * D_, alnb + l * D_, Wqn, qkvn);
    k_eattn<<<RN_, 256, 0, stream>>>(ein, qkvn, wq_fm + (size_t)l * 49152,
                                     elng + l * D_, elnb + l * D_, stats, rmean, obuf);
    k_nodemlp<<<GM, 256, 0, stream>>>(node, obuf, WcN + (size_t)l * DD, bcN + l * D_,
                                      nlng + l * D_, nlnb + l * D_,
                                      nW1 + (size_t)l * D_ * 256, nb1 + l * 256,
                                      nW2 + (size_t)l * 256 * D_, nb2 + l * D_);

    k_colmean<<<RN_, 128, 0, stream>>>(ein, stats, elng + l * D_, elnb + l * D_, cmean);
    k_nvec<<<dim3(GN, 2, 2), 256, 0, stream>>>(node, rmean, cmean,
                                               Ws + (size_t)l * DD, Wer + (size_t)l * DD,
                                               Wt + (size_t)l * DD, Wec + (size_t)l * DD,
                                               bs + l * D_, be + l * D_, bt + l * D_,
                                               rvec, cvec);

    k_fedge<<<GE, 256, 0, stream>>>(ein, eout, stats,
                                    elng + l * D_, elnb + l * D_,
                                    we_fm + (size_t)l * 32768, rvec, cvec,
                                    wce_fm + (size_t)l * 16384, bcE + l * D_,
                                    mlng + l * D_, mlnb + l * D_,
                                    w1_fm + (size_t)l * 32768, mb1 + l * 256,
                                    w2_fm + (size_t)l * 32768, mb2 + l * D_);
  }

  k_head<<<B_, 128, 0, stream>>>(node, Wo1, bo1, Wo2, bo2, outp);
}